// Round 2
// baseline (1023.483 us; speedup 1.0000x reference)
//
#include <hip/hip_runtime.h>
#include <hip/hip_bf16.h>

#define Nn 50000
#define Ee 1000000
#define Bb 512

typedef unsigned int u32;

// ---------------- input projection: X = x @ W_in + b_in ----------------
__global__ __launch_bounds__(256) void k_input_proj(const float* __restrict__ x,
    const float* __restrict__ Win, const float* __restrict__ bin, float* __restrict__ X)
{
    __shared__ float W[8][64];
    __shared__ float bsh[64];
    int t = threadIdx.x;
    if (t < 64) bsh[t] = bin[t];
    for (int i = t; i < 512; i += 256) W[i >> 6][i & 63] = Win[i];
    __syncthreads();
    int gid = blockIdx.x * 256 + t;
    int n = gid >> 6, c = gid & 63;
    const float* xr = x + n * 8;
    float acc = bsh[c];
#pragma unroll
    for (int k = 0; k < 8; ++k) acc = fmaf(xr[k], W[k][c], acc);
    X[gid] = acc;
}

// ---------------- CSR build ----------------
__global__ __launch_bounds__(256) void k_hist(const int* __restrict__ ei, int* __restrict__ deg)
{
    int e = blockIdx.x * 256 + threadIdx.x;
    if (e < Ee) atomicAdd(&deg[ei[Ee + e]], 1);
}

__global__ __launch_bounds__(1024) void k_scan(const int* __restrict__ deg, int* __restrict__ rowptr)
{
    __shared__ int wsum[16];
    __shared__ int carry;
    int t = threadIdx.x, lane = t & 63, w = t >> 6;
    if (t == 0) { carry = 0; rowptr[0] = 0; }
    __syncthreads();
    for (int base = 0; base < Nn; base += 1024) {
        int idx = base + t;
        int v = (idx < Nn) ? deg[idx] : 0;
        int s = v;
#pragma unroll
        for (int off = 1; off < 64; off <<= 1) {
            int u = __shfl_up(s, off);
            if (lane >= off) s += u;
        }
        if (lane == 63) wsum[w] = s;
        __syncthreads();
        if (t == 0) {
            int a = 0;
#pragma unroll
            for (int i = 0; i < 16; ++i) { a += wsum[i]; wsum[i] = a; }
        }
        __syncthreads();
        int excl = (w == 0 ? 0 : wsum[w - 1]) + carry;
        if (idx < Nn) rowptr[idx + 1] = excl + s;
        __syncthreads();
        if (t == 0) carry += wsum[15];
        __syncthreads();
    }
}

__global__ __launch_bounds__(256) void k_scatter(const int* __restrict__ ei, const float* __restrict__ eattr,
    const int* __restrict__ rowptr, int* __restrict__ cursor, int* __restrict__ colsrc,
    float4* __restrict__ ea4)
{
    int e = blockIdx.x * 256 + threadIdx.x;
    if (e >= Ee) return;
    int d = ei[Ee + e];
    int pos = rowptr[d] + atomicAdd(&cursor[d], 1);
    colsrc[pos] = ei[e];
    ea4[pos] = *(const float4*)(eattr + (size_t)e * 4);
}

// ---------------- fused LN1 + [Q|K] / [V|Skip] projections ----------------
// tile: 128 rows x 128 cols, K=64. thread: 8x8. QKVS row layout: [q(64)|k(64)|v(64)|xr(64)]
__global__ __launch_bounds__(256) void k_ln_proj(
    const float* __restrict__ X, float* __restrict__ QKVS,
    const float* __restrict__ Wq, const float* __restrict__ Wk,
    const float* __restrict__ Wv, const float* __restrict__ Ws,
    const float* __restrict__ bq, const float* __restrict__ bk,
    const float* __restrict__ bv, const float* __restrict__ bs,
    const float* __restrict__ lng, const float* __restrict__ lnb)
{
    __shared__ float HT[64][132];   // [k][row]
    __shared__ float WT[64][128];   // [k][col]
    __shared__ float BS[128];
    const int t = threadIdx.x;
    const int row0 = blockIdx.x * 128;
    const int ct = blockIdx.y;
    const float* Wa = ct ? Wv : Wq;
    const float* Wb = ct ? Ws : Wk;
    const float* ba = ct ? bv : bq;
    const float* bb = ct ? bs : bk;
    for (int i = t; i < 64 * 128; i += 256) {
        int k = i >> 7, c = i & 127;
        WT[k][c] = (c < 64) ? Wa[k * 64 + c] : Wb[k * 64 + c - 64];
    }
    if (t < 128) BS[t] = (t < 64) ? ba[t] : bb[t - 64];
    {
        const int wv_ = t >> 6, ln = t & 63;
        const float g = lng[ln], b = lnb[ln];
        for (int r = wv_; r < 128; r += 4) {
            int n = row0 + r;
            float v = (n < Nn) ? X[(size_t)n * 64 + ln] : 0.f;
            float s = v;
#pragma unroll
            for (int off = 32; off; off >>= 1) s += __shfl_xor(s, off);
            float mu = s * 0.015625f;
            float d = v - mu;
            float s2 = d * d;
#pragma unroll
            for (int off = 32; off; off >>= 1) s2 += __shfl_xor(s2, off);
            float rstd = rsqrtf(s2 * 0.015625f + 1e-5f);
            HT[ln][r] = d * rstd * g + b;
        }
    }
    __syncthreads();
    const int r0 = (t >> 4) * 8, c0 = (t & 15) * 8;
    float acc[8][8];
#pragma unroll
    for (int i = 0; i < 8; ++i)
#pragma unroll
        for (int j = 0; j < 8; ++j) acc[i][j] = 0.f;
    for (int k = 0; k < 64; ++k) {
        const float4 h0 = *(const float4*)&HT[k][r0];
        const float4 h1 = *(const float4*)&HT[k][r0 + 4];
        const float4 w0 = *(const float4*)&WT[k][c0];
        const float4 w1 = *(const float4*)&WT[k][c0 + 4];
        float hv[8] = {h0.x, h0.y, h0.z, h0.w, h1.x, h1.y, h1.z, h1.w};
        float wv2[8] = {w0.x, w0.y, w0.z, w0.w, w1.x, w1.y, w1.z, w1.w};
#pragma unroll
        for (int i = 0; i < 8; ++i)
#pragma unroll
            for (int j = 0; j < 8; ++j) acc[i][j] = fmaf(hv[i], wv2[j], acc[i][j]);
    }
    const int colOff = ct * 128;
#pragma unroll
    for (int i = 0; i < 8; ++i) {
        int n = row0 + r0 + i;
        if (n >= Nn) continue;
        float* dst = QKVS + (size_t)n * 256 + colOff + c0;
        float4 o0 = make_float4(acc[i][0] + BS[c0], acc[i][1] + BS[c0 + 1],
                                acc[i][2] + BS[c0 + 2], acc[i][3] + BS[c0 + 3]);
        float4 o1 = make_float4(acc[i][4] + BS[c0 + 4], acc[i][5] + BS[c0 + 5],
                                acc[i][6] + BS[c0 + 6], acc[i][7] + BS[c0 + 7]);
        *(float4*)dst = o0;
        *((float4*)dst + 1) = o1;
    }
}

// ---------------- edge attention (one wave per node, online softmax) + beta gate + residual -----
__global__ __launch_bounds__(256) void k_edge(
    const float* __restrict__ QKVS, float* __restrict__ X,
    const int* __restrict__ rowptr, const int* __restrict__ colsrc,
    const float4* __restrict__ ea4,
    const float* __restrict__ We, const float* __restrict__ Wbeta)
{
    int lane = threadIdx.x & 63;
    int node = blockIdx.x * 4 + (threadIdx.x >> 6);
    if (node >= Nn) return;
    float we0 = We[lane], we1 = We[64 + lane];
    float we2 = We[128 + lane], we3 = We[192 + lane];
    float wbA = Wbeta[lane] + Wbeta[128 + lane];
    float wbB = Wbeta[64 + lane] - Wbeta[128 + lane];
    const float* qrow = QKVS + (size_t)node * 256;
    float q = qrow[lane];
    float xr = qrow[192 + lane];
    int jb = rowptr[node], je = rowptr[node + 1];
    float m = -1e30f, lsum = 0.f, acc = 0.f;
    for (int j = jb; j < je; ++j) {
        int src = colsrc[j];
        float4 ea = ea4[j];
        float e = we0 * ea.x;
        e = fmaf(we1, ea.y, e);
        e = fmaf(we2, ea.z, e);
        e = fmaf(we3, ea.w, e);
        const float* srow = QKVS + (size_t)src * 256;
        float ke = srow[64 + lane] + e;
        float ve = srow[128 + lane] + e;
        float p = q * ke;
        p += __shfl_xor(p, 1);
        p += __shfl_xor(p, 2);
        p += __shfl_xor(p, 4);
        p += __shfl_xor(p, 8);
        float s = p * 0.25f;
        float mn = fmaxf(m, s);
        float corr = __expf(m - mn);
        float pe = __expf(s - mn);
        lsum = lsum * corr + pe;
        acc = acc * corr + pe * ve;
        m = mn;
    }
    float outv = acc / (lsum + 1e-16f);
    float tb = outv * wbA + xr * wbB;
#pragma unroll
    for (int off = 32; off; off >>= 1) tb += __shfl_xor(tb, off);
    float beta = 1.f / (1.f + __expf(-tb));
    float res = beta * xr + (1.f - beta) * outv;
    X[(size_t)node * 64 + lane] += res;
}

// ---------------- fused LN2 + FFN1 (64->128) + GELU ----------------
__global__ __launch_bounds__(256) void k_ln_ffn1(
    const float* __restrict__ X, float* __restrict__ G,
    const float* __restrict__ W1, const float* __restrict__ b1,
    const float* __restrict__ lng, const float* __restrict__ lnb)
{
    __shared__ float HT[64][132];
    __shared__ float WT[64][128];
    __shared__ float BS[128];
    const int t = threadIdx.x;
    const int row0 = blockIdx.x * 128;
    for (int i = t; i < 64 * 128; i += 256) WT[i >> 7][i & 127] = W1[i];
    if (t < 128) BS[t] = b1[t];
    {
        const int wv_ = t >> 6, ln = t & 63;
        const float g = lng[ln], b = lnb[ln];
        for (int r = wv_; r < 128; r += 4) {
            int n = row0 + r;
            float v = (n < Nn) ? X[(size_t)n * 64 + ln] : 0.f;
            float s = v;
#pragma unroll
            for (int off = 32; off; off >>= 1) s += __shfl_xor(s, off);
            float mu = s * 0.015625f;
            float d = v - mu;
            float s2 = d * d;
#pragma unroll
            for (int off = 32; off; off >>= 1) s2 += __shfl_xor(s2, off);
            float rstd = rsqrtf(s2 * 0.015625f + 1e-5f);
            HT[ln][r] = d * rstd * g + b;
        }
    }
    __syncthreads();
    const int r0 = (t >> 4) * 8, c0 = (t & 15) * 8;
    float acc[8][8];
#pragma unroll
    for (int i = 0; i < 8; ++i)
#pragma unroll
        for (int j = 0; j < 8; ++j) acc[i][j] = 0.f;
    for (int k = 0; k < 64; ++k) {
        const float4 h0 = *(const float4*)&HT[k][r0];
        const float4 h1 = *(const float4*)&HT[k][r0 + 4];
        const float4 w0 = *(const float4*)&WT[k][c0];
        const float4 w1 = *(const float4*)&WT[k][c0 + 4];
        float hv[8] = {h0.x, h0.y, h0.z, h0.w, h1.x, h1.y, h1.z, h1.w};
        float wv2[8] = {w0.x, w0.y, w0.z, w0.w, w1.x, w1.y, w1.z, w1.w};
#pragma unroll
        for (int i = 0; i < 8; ++i)
#pragma unroll
            for (int j = 0; j < 8; ++j) acc[i][j] = fmaf(hv[i], wv2[j], acc[i][j]);
    }
#pragma unroll
    for (int i = 0; i < 8; ++i) {
        int n = row0 + r0 + i;
        if (n >= Nn) continue;
        float* dst = G + (size_t)n * 128 + c0;
        float o[8];
#pragma unroll
        for (int j = 0; j < 8; ++j) {
            float v = acc[i][j] + BS[c0 + j];
            o[j] = 0.5f * v * (1.f + erff(v * 0.7071067811865476f));
        }
        *(float4*)dst = make_float4(o[0], o[1], o[2], o[3]);
        *((float4*)dst + 1) = make_float4(o[4], o[5], o[6], o[7]);
    }
}

// ---------------- FFN2 (128->64) + residual add into X ----------------
__global__ __launch_bounds__(256) void k_ffn2(
    const float* __restrict__ G, float* __restrict__ X,
    const float* __restrict__ W2, const float* __restrict__ b2)
{
    __shared__ float GT[64][132];    // [k-chunk][row]
    __shared__ float WT[128][64];
    __shared__ float BS[64];
    const int t = threadIdx.x;
    const int row0 = blockIdx.x * 128;
    for (int i = t; i < 128 * 64; i += 256) WT[i >> 6][i & 63] = W2[i];
    if (t < 64) BS[t] = b2[t];
    const int r0 = (t >> 4) * 8, c0 = (t & 15) * 4;
    float acc[8][4];
#pragma unroll
    for (int i = 0; i < 8; ++i)
#pragma unroll
        for (int j = 0; j < 4; ++j) acc[i][j] = 0.f;
    for (int ks = 0; ks < 128; ks += 64) {
        __syncthreads();
        for (int i = t; i < 64 * 128; i += 256) {
            int kk = i & 63, r = i >> 6;
            int n = row0 + r;
            GT[kk][r] = (n < Nn) ? G[(size_t)n * 128 + ks + kk] : 0.f;
        }
        __syncthreads();
        for (int kk = 0; kk < 64; ++kk) {
            const float4 h0 = *(const float4*)&GT[kk][r0];
            const float4 h1 = *(const float4*)&GT[kk][r0 + 4];
            const float4 w = *(const float4*)&WT[ks + kk][c0];
            float hv[8] = {h0.x, h0.y, h0.z, h0.w, h1.x, h1.y, h1.z, h1.w};
            float wv2[4] = {w.x, w.y, w.z, w.w};
#pragma unroll
            for (int i = 0; i < 8; ++i)
#pragma unroll
                for (int j = 0; j < 4; ++j) acc[i][j] = fmaf(hv[i], wv2[j], acc[i][j]);
        }
    }
#pragma unroll
    for (int i = 0; i < 8; ++i) {
        int n = row0 + r0 + i;
        if (n >= Nn) continue;
        float* dst = X + (size_t)n * 64 + c0;
        float4 xv = *(float4*)dst;
        xv.x += acc[i][0] + BS[c0];
        xv.y += acc[i][1] + BS[c0 + 1];
        xv.z += acc[i][2] + BS[c0 + 2];
        xv.w += acc[i][3] + BS[c0 + 3];
        *(float4*)dst = xv;
    }
}

// ---------------- segment-max pool (monotone-uint atomicMax) ----------------
__global__ __launch_bounds__(256) void k_pool(const float* __restrict__ X,
    const int* __restrict__ batch, u32* __restrict__ pkeys)
{
    int gid = blockIdx.x * 256 + threadIdx.x;
    int n = gid >> 6, c = gid & 63;
    float v = X[gid];
    u32 u = __float_as_uint(v);
    u32 key = (u >> 31) ? ~u : (u | 0x80000000u);
    atomicMax(&pkeys[batch[n] * 64 + c], key);
}

// ---------------- head: relu(pooled@Wo1+bo1)@Wo2+bo2, L2-normalize ----------------
__global__ __launch_bounds__(128) void k_head(const u32* __restrict__ pkeys,
    const float* __restrict__ Wo1, const float* __restrict__ bo1,
    const float* __restrict__ Wo2, const float* __restrict__ bo2,
    float* __restrict__ out)
{
    __shared__ float P[64];
    __shared__ float E1[128];
    __shared__ float wred[2];
    int b = blockIdx.x, t = threadIdx.x;
    if (t < 64) {
        u32 k = pkeys[b * 64 + t];
        float v = 0.f;
        if (k) v = (k >> 31) ? __uint_as_float(k ^ 0x80000000u) : __uint_as_float(~k);
        P[t] = v;
    }
    __syncthreads();
    float a = bo1[t];
#pragma unroll 8
    for (int k = 0; k < 64; ++k) a = fmaf(P[k], Wo1[k * 128 + t], a);
    E1[t] = fmaxf(a, 0.f);
    __syncthreads();
    float o = bo2[t];
#pragma unroll 8
    for (int k = 0; k < 128; ++k) o = fmaf(E1[k], Wo2[k * 128 + t], o);
    float ss = o * o;
#pragma unroll
    for (int off = 32; off; off >>= 1) ss += __shfl_xor(ss, off);
    if ((t & 63) == 0) wred[t >> 6] = ss;
    __syncthreads();
    float tot = wred[0] + wred[1];
    float nrm = fmaxf(sqrtf(tot), 1e-12f);
    out[b * 128 + t] = o / nrm;
}

// ---------------- launch ----------------
extern "C" void kernel_launch(void* const* d_in, const int* in_sizes, int n_in,
                              void* d_out, int out_size, void* d_ws, size_t ws_size,
                              hipStream_t stream)
{
    const float* x         = (const float*)d_in[0];
    const float* edge_attr = (const float*)d_in[1];
    const int* ei          = (const int*)d_in[2];
    const int* batch       = (const int*)d_in[3];
    const float* Win  = (const float*)d_in[4];
    const float* bin  = (const float*)d_in[5];
    const float* ln1g = (const float*)d_in[6];
    const float* ln1b = (const float*)d_in[7];
    const float* Wq   = (const float*)d_in[8];
    const float* bq   = (const float*)d_in[9];
    const float* Wk   = (const float*)d_in[10];
    const float* bk   = (const float*)d_in[11];
    const float* Wv   = (const float*)d_in[12];
    const float* bv   = (const float*)d_in[13];
    const float* We   = (const float*)d_in[14];
    const float* Wsk  = (const float*)d_in[15];
    const float* bsk  = (const float*)d_in[16];
    const float* Wbe  = (const float*)d_in[17];
    const float* ln2g = (const float*)d_in[18];
    const float* ln2b = (const float*)d_in[19];
    const float* W1   = (const float*)d_in[20];
    const float* b1   = (const float*)d_in[21];
    const float* W2   = (const float*)d_in[22];
    const float* b2   = (const float*)d_in[23];
    const float* Wo1  = (const float*)d_in[24];
    const float* bo1  = (const float*)d_in[25];
    const float* Wo2  = (const float*)d_in[26];
    const float* bo2  = (const float*)d_in[27];

    char* wsp = (char*)d_ws;
    size_t off = 0;
    auto alloc = [&](size_t bytes) { void* p = wsp + off; off = (off + bytes + 255) & ~(size_t)255; return p; };
    float*   X      = (float*)alloc((size_t)Nn * 64 * 4);
    float*   QKVS   = (float*)alloc((size_t)Nn * 256 * 4);
    float*   G      = (float*)alloc((size_t)Nn * 128 * 4);
    int*     rowptr = (int*)alloc((size_t)(Nn + 1) * 4);
    int*     deg    = (int*)alloc((size_t)Nn * 4);
    int*     cursor = (int*)alloc((size_t)Nn * 4);
    int*     colsrc = (int*)alloc((size_t)Ee * 4);
    float4*  ea4    = (float4*)alloc((size_t)Ee * 16);
    u32*     pkeys  = (u32*)alloc((size_t)Bb * 64 * 4);

    hipMemsetAsync(deg, 0, (size_t)Nn * 4, stream);
    hipMemsetAsync(cursor, 0, (size_t)Nn * 4, stream);
    hipMemsetAsync(pkeys, 0, (size_t)Bb * 64 * 4, stream);

    k_input_proj<<<12500, 256, 0, stream>>>(x, Win, bin, X);
    k_hist<<<(Ee + 255) / 256, 256, 0, stream>>>(ei, deg);
    k_scan<<<1, 1024, 0, stream>>>(deg, rowptr);
    k_scatter<<<(Ee + 255) / 256, 256, 0, stream>>>(ei, edge_attr, rowptr, cursor, colsrc, ea4);

    const int gb = (Nn + 127) / 128;  // 391
    for (int l = 0; l < 3; ++l) {
        k_ln_proj<<<dim3(gb, 2), 256, 0, stream>>>(X, QKVS,
            Wq + l * 4096, Wk + l * 4096, Wv + l * 4096, Wsk + l * 4096,
            bq + l * 64, bk + l * 64, bv + l * 64, bsk + l * 64,
            ln1g + l * 64, ln1b + l * 64);
        k_edge<<<Nn / 4, 256, 0, stream>>>(QKVS, X, rowptr, colsrc, ea4,
            We + l * 256, Wbe + l * 192);
        k_ln_ffn1<<<gb, 256, 0, stream>>>(X, G, W1 + l * 8192, b1 + l * 128,
            ln2g + l * 64, ln2b + l * 64);
        k_ffn2<<<gb, 256, 0, stream>>>(G, X, W2 + l * 8192, b2 + l * 64);
    }
    k_pool<<<12500, 256, 0, stream>>>(X, batch, pkeys);
    k_head<<<Bb, 128, 0, stream>>>(pkeys, Wo1, bo1, Wo2, bo2, (float*)d_out);
}

// Round 3
// 1017.555 us; speedup vs baseline: 1.0058x; 1.0058x over previous
//
#include <hip/hip_runtime.h>
#include <hip/hip_bf16.h>
#include <hip/hip_fp16.h>

#define Nn 50000
#define Ee 1000000
#define Bb 512

typedef unsigned short u16;
typedef unsigned int u32;

__device__ __forceinline__ u16 f2h(float f) {
    return __half_as_ushort(__float2half(f));
}
__device__ __forceinline__ float h2f_lo(u32 kv) {
    return __half2float(__ushort_as_half((u16)(kv & 0xffff)));
}
__device__ __forceinline__ float h2f_hi(u32 kv) {
    return __half2float(__ushort_as_half((u16)(kv >> 16)));
}

// ---------------- input projection: X = x @ W_in + b_in ----------------
__global__ __launch_bounds__(256) void k_input_proj(const float* __restrict__ x,
    const float* __restrict__ Win, const float* __restrict__ bin, float* __restrict__ X)
{
    __shared__ float W[8][64];
    __shared__ float bsh[64];
    int t = threadIdx.x;
    if (t < 64) bsh[t] = bin[t];
    for (int i = t; i < 512; i += 256) W[i >> 6][i & 63] = Win[i];
    __syncthreads();
    int gid = blockIdx.x * 256 + t;
    int n = gid >> 6, c = gid & 63;
    const float* xr = x + n * 8;
    float acc = bsh[c];
#pragma unroll
    for (int k = 0; k < 8; ++k) acc = fmaf(xr[k], W[k][c], acc);
    X[gid] = acc;
}

// ---------------- CSR build ----------------
__global__ __launch_bounds__(256) void k_hist(const int* __restrict__ ei, int* __restrict__ deg)
{
    int e = blockIdx.x * 256 + threadIdx.x;
    if (e < Ee) atomicAdd(&deg[ei[Ee + e]], 1);
}

// single block, 1024 threads, chunked 2-pass scan (3 barriers)
__global__ __launch_bounds__(1024) void k_scan(const int* __restrict__ deg, int* __restrict__ rowptr)
{
    __shared__ int wsum[16];
    const int C = 49;  // 49*1024 = 50176 >= Nn
    int t = threadIdx.x, lane = t & 63, w = t >> 6;
    int start = t * C;
    int s = 0;
#pragma unroll 7
    for (int i = 0; i < C; ++i) {
        int idx = start + i;
        if (idx < Nn) s += deg[idx];
    }
    int sc = s;
#pragma unroll
    for (int off = 1; off < 64; off <<= 1) {
        int u = __shfl_up(sc, off);
        if (lane >= off) sc += u;
    }
    if (lane == 63) wsum[w] = sc;
    __syncthreads();
    if (t == 0) {
        int a = 0;
#pragma unroll
        for (int i = 0; i < 16; ++i) { a += wsum[i]; wsum[i] = a; }
    }
    __syncthreads();
    int run = sc - s + (w ? wsum[w - 1] : 0);
    for (int i = 0; i < C; ++i) {
        int idx = start + i;
        if (idx < Nn) { run += deg[idx]; rowptr[idx + 1] = run; }
    }
    if (t == 0) rowptr[0] = 0;
}

__global__ __launch_bounds__(256) void k_scatter(const int* __restrict__ ei, const float* __restrict__ eattr,
    const int* __restrict__ rowptr, int* __restrict__ cursor, int* __restrict__ colsrc,
    float4* __restrict__ ea4)
{
    int e = blockIdx.x * 256 + threadIdx.x;
    if (e >= Ee) return;
    int d = ei[Ee + e];
    int pos = rowptr[d] + atomicAdd(&cursor[d], 1);
    colsrc[pos] = ei[e];
    ea4[pos] = *(const float4*)(eattr + (size_t)e * 4);
}

// ---------------- fused LN1 + [Q|K] / [V|Skip] projections ----------------
// QX row: [q(64 f32)|xr(64 f32)]; KV row: 64 u32, u32 = (v_f16 << 16) | k_f16 per channel
__global__ __launch_bounds__(256) void k_ln_proj(
    const float* __restrict__ X, float* __restrict__ QX, u32* __restrict__ KV,
    const float* __restrict__ Wq, const float* __restrict__ Wk,
    const float* __restrict__ Wv, const float* __restrict__ Ws,
    const float* __restrict__ bq, const float* __restrict__ bk,
    const float* __restrict__ bv, const float* __restrict__ bs,
    const float* __restrict__ lng, const float* __restrict__ lnb)
{
    __shared__ float HT[64][132];   // [k][row]
    __shared__ float WT[64][128];   // [k][col]
    __shared__ float BS[128];
    const int t = threadIdx.x;
    const int row0 = blockIdx.x * 128;
    const int ct = blockIdx.y;
    const float* Wa = ct ? Wv : Wq;
    const float* Wb = ct ? Ws : Wk;
    const float* ba = ct ? bv : bq;
    const float* bb = ct ? bs : bk;
    for (int i = t; i < 64 * 128; i += 256) {
        int k = i >> 7, c = i & 127;
        WT[k][c] = (c < 64) ? Wa[k * 64 + c] : Wb[k * 64 + c - 64];
    }
    if (t < 128) BS[t] = (t < 64) ? ba[t] : bb[t - 64];
    {
        const int wv_ = t >> 6, ln = t & 63;
        const float g = lng[ln], b = lnb[ln];
        for (int r = wv_; r < 128; r += 4) {
            int n = row0 + r;
            float v = (n < Nn) ? X[(size_t)n * 64 + ln] : 0.f;
            float s = v;
#pragma unroll
            for (int off = 32; off; off >>= 1) s += __shfl_xor(s, off);
            float mu = s * 0.015625f;
            float d = v - mu;
            float s2 = d * d;
#pragma unroll
            for (int off = 32; off; off >>= 1) s2 += __shfl_xor(s2, off);
            float rstd = rsqrtf(s2 * 0.015625f + 1e-5f);
            HT[ln][r] = d * rstd * g + b;
        }
    }
    __syncthreads();
    const int r0 = (t >> 4) * 8, c0 = (t & 15) * 8;
    float acc[8][8];
#pragma unroll
    for (int i = 0; i < 8; ++i)
#pragma unroll
        for (int j = 0; j < 8; ++j) acc[i][j] = 0.f;
    for (int k = 0; k < 64; ++k) {
        const float4 h0 = *(const float4*)&HT[k][r0];
        const float4 h1 = *(const float4*)&HT[k][r0 + 4];
        const float4 w0 = *(const float4*)&WT[k][c0];
        const float4 w1 = *(const float4*)&WT[k][c0 + 4];
        float hv[8] = {h0.x, h0.y, h0.z, h0.w, h1.x, h1.y, h1.z, h1.w};
        float wv2[8] = {w0.x, w0.y, w0.z, w0.w, w1.x, w1.y, w1.z, w1.w};
#pragma unroll
        for (int i = 0; i < 8; ++i)
#pragma unroll
            for (int j = 0; j < 8; ++j) acc[i][j] = fmaf(hv[i], wv2[j], acc[i][j]);
    }
    const bool isFloat = (c0 < 64) == (ct == 0);  // ct0:q cols<64 ; ct1:xr cols>=64
#pragma unroll
    for (int i = 0; i < 8; ++i) {
        int n = row0 + r0 + i;
        if (n >= Nn) continue;
        if (isFloat) {
            float* dst = QX + (size_t)n * 128 + c0;
            float4 o0 = make_float4(acc[i][0] + BS[c0], acc[i][1] + BS[c0 + 1],
                                    acc[i][2] + BS[c0 + 2], acc[i][3] + BS[c0 + 3]);
            float4 o1 = make_float4(acc[i][4] + BS[c0 + 4], acc[i][5] + BS[c0 + 5],
                                    acc[i][6] + BS[c0 + 6], acc[i][7] + BS[c0 + 7]);
            *(float4*)dst = o0;
            *((float4*)dst + 1) = o1;
        } else {
            int ch = (ct == 0) ? (c0 - 64) : c0;
            u16* dst = (u16*)(KV + (size_t)n * 64 + ch) + (ct == 0 ? 0 : 1);
#pragma unroll
            for (int j = 0; j < 8; ++j) dst[2 * j] = f2h(acc[i][j] + BS[c0 + j]);
        }
    }
}

// ---------------- edge attention: one wave/node, 2-way interleaved online softmax ----------------
__global__ __launch_bounds__(256) void k_edge(
    const float* __restrict__ QX, const u32* __restrict__ KV, float* __restrict__ X,
    const int* __restrict__ rowptr, const int* __restrict__ colsrc,
    const float4* __restrict__ ea4,
    const float* __restrict__ We, const float* __restrict__ Wbeta)
{
    int lane = threadIdx.x & 63;
    int node = blockIdx.x * 4 + (threadIdx.x >> 6);
    if (node >= Nn) return;
    float we0 = We[lane], we1 = We[64 + lane];
    float we2 = We[128 + lane], we3 = We[192 + lane];
    float wbA = Wbeta[lane] + Wbeta[128 + lane];
    float wbB = Wbeta[64 + lane] - Wbeta[128 + lane];
    const float* qrow = QX + (size_t)node * 128;
    float q = qrow[lane];
    float xr = qrow[64 + lane];
    int jb = rowptr[node], je = rowptr[node + 1];
    float m0 = -1e30f, l0 = 0.f, a0 = 0.f;
    float m1 = -1e30f, l1 = 0.f, a1 = 0.f;
    int j = jb;
    for (; j + 1 < je; j += 2) {
        int s0 = colsrc[j], s1 = colsrc[j + 1];
        float4 eb0 = ea4[j], eb1 = ea4[j + 1];
        u32 kv0 = KV[(size_t)s0 * 64 + lane];
        u32 kv1 = KV[(size_t)s1 * 64 + lane];
        float e0 = we0 * eb0.x;
        e0 = fmaf(we1, eb0.y, e0); e0 = fmaf(we2, eb0.z, e0); e0 = fmaf(we3, eb0.w, e0);
        float e1 = we0 * eb1.x;
        e1 = fmaf(we1, eb1.y, e1); e1 = fmaf(we2, eb1.z, e1); e1 = fmaf(we3, eb1.w, e1);
        float ke0 = h2f_lo(kv0) + e0, ve0 = h2f_hi(kv0) + e0;
        float ke1 = h2f_lo(kv1) + e1, ve1 = h2f_hi(kv1) + e1;
        float p0 = q * ke0, p1 = q * ke1;
        p0 += __shfl_xor(p0, 1); p1 += __shfl_xor(p1, 1);
        p0 += __shfl_xor(p0, 2); p1 += __shfl_xor(p1, 2);
        p0 += __shfl_xor(p0, 4); p1 += __shfl_xor(p1, 4);
        p0 += __shfl_xor(p0, 8); p1 += __shfl_xor(p1, 8);
        float sA = p0 * 0.25f, sB = p1 * 0.25f;
        float mnA = fmaxf(m0, sA), mnB = fmaxf(m1, sB);
        float cA = __expf(m0 - mnA), cB = __expf(m1 - mnB);
        float pA = __expf(sA - mnA), pB = __expf(sB - mnB);
        l0 = l0 * cA + pA;            l1 = l1 * cB + pB;
        a0 = a0 * cA + pA * ve0;      a1 = a1 * cB + pB * ve1;
        m0 = mnA;                     m1 = mnB;
    }
    if (j < je) {
        int s0 = colsrc[j];
        float4 eb0 = ea4[j];
        u32 kv0 = KV[(size_t)s0 * 64 + lane];
        float e0 = we0 * eb0.x;
        e0 = fmaf(we1, eb0.y, e0); e0 = fmaf(we2, eb0.z, e0); e0 = fmaf(we3, eb0.w, e0);
        float ke0 = h2f_lo(kv0) + e0, ve0 = h2f_hi(kv0) + e0;
        float p0 = q * ke0;
        p0 += __shfl_xor(p0, 1);
        p0 += __shfl_xor(p0, 2);
        p0 += __shfl_xor(p0, 4);
        p0 += __shfl_xor(p0, 8);
        float sA = p0 * 0.25f;
        float mnA = fmaxf(m0, sA);
        float cA = __expf(m0 - mnA);
        float pA = __expf(sA - mnA);
        l0 = l0 * cA + pA;
        a0 = a0 * cA + pA * ve0;
        m0 = mnA;
    }
    // merge partials
    float mn = fmaxf(m0, m1);
    float c0 = __expf(m0 - mn), c1 = __expf(m1 - mn);
    float lsum = l0 * c0 + l1 * c1;
    float acc = a0 * c0 + a1 * c1;
    float outv = acc / (lsum + 1e-16f);
    float tb = outv * wbA + xr * wbB;
#pragma unroll
    for (int off = 32; off; off >>= 1) tb += __shfl_xor(tb, off);
    float beta = 1.f / (1.f + __expf(-tb));
    float res = beta * xr + (1.f - beta) * outv;
    X[(size_t)node * 64 + lane] += res;
}

// ---------------- fused LN2 + FFN1 (64->128) + GELU ----------------
__global__ __launch_bounds__(256) void k_ln_ffn1(
    const float* __restrict__ X, float* __restrict__ G,
    const float* __restrict__ W1, const float* __restrict__ b1,
    const float* __restrict__ lng, const float* __restrict__ lnb)
{
    __shared__ float HT[64][132];
    __shared__ float WT[64][128];
    __shared__ float BS[128];
    const int t = threadIdx.x;
    const int row0 = blockIdx.x * 128;
    for (int i = t; i < 64 * 128; i += 256) WT[i >> 7][i & 127] = W1[i];
    if (t < 128) BS[t] = b1[t];
    {
        const int wv_ = t >> 6, ln = t & 63;
        const float g = lng[ln], b = lnb[ln];
        for (int r = wv_; r < 128; r += 4) {
            int n = row0 + r;
            float v = (n < Nn) ? X[(size_t)n * 64 + ln] : 0.f;
            float s = v;
#pragma unroll
            for (int off = 32; off; off >>= 1) s += __shfl_xor(s, off);
            float mu = s * 0.015625f;
            float d = v - mu;
            float s2 = d * d;
#pragma unroll
            for (int off = 32; off; off >>= 1) s2 += __shfl_xor(s2, off);
            float rstd = rsqrtf(s2 * 0.015625f + 1e-5f);
            HT[ln][r] = d * rstd * g + b;
        }
    }
    __syncthreads();
    const int r0 = (t >> 4) * 8, c0 = (t & 15) * 8;
    float acc[8][8];
#pragma unroll
    for (int i = 0; i < 8; ++i)
#pragma unroll
        for (int j = 0; j < 8; ++j) acc[i][j] = 0.f;
    for (int k = 0; k < 64; ++k) {
        const float4 h0 = *(const float4*)&HT[k][r0];
        const float4 h1 = *(const float4*)&HT[k][r0 + 4];
        const float4 w0 = *(const float4*)&WT[k][c0];
        const float4 w1 = *(const float4*)&WT[k][c0 + 4];
        float hv[8] = {h0.x, h0.y, h0.z, h0.w, h1.x, h1.y, h1.z, h1.w};
        float wv2[8] = {w0.x, w0.y, w0.z, w0.w, w1.x, w1.y, w1.z, w1.w};
#pragma unroll
        for (int i = 0; i < 8; ++i)
#pragma unroll
            for (int j = 0; j < 8; ++j) acc[i][j] = fmaf(hv[i], wv2[j], acc[i][j]);
    }
#pragma unroll
    for (int i = 0; i < 8; ++i) {
        int n = row0 + r0 + i;
        if (n >= Nn) continue;
        float* dst = G + (size_t)n * 128 + c0;
        float o[8];
#pragma unroll
        for (int j = 0; j < 8; ++j) {
            float v = acc[i][j] + BS[c0 + j];
            o[j] = 0.5f * v * (1.f + erff(v * 0.7071067811865476f));
        }
        *(float4*)dst = make_float4(o[0], o[1], o[2], o[3]);
        *((float4*)dst + 1) = make_float4(o[4], o[5], o[6], o[7]);
    }
}

// ---------------- FFN2 (128->64) + residual add into X (+ optional fused pool) ----------------
__global__ __launch_bounds__(256) void k_ffn2(
    const float* __restrict__ G, float* __restrict__ X,
    const float* __restrict__ W2, const float* __restrict__ b2,
    const int* __restrict__ batch, u32* __restrict__ pkeys, int dopool)
{
    __shared__ float GT[64][132];    // [k-chunk][row]
    __shared__ float WT[128][64];
    __shared__ float BS[64];
    const int t = threadIdx.x;
    const int row0 = blockIdx.x * 128;
    for (int i = t; i < 128 * 64; i += 256) WT[i >> 6][i & 63] = W2[i];
    if (t < 64) BS[t] = b2[t];
    const int r0 = (t >> 4) * 8, c0 = (t & 15) * 4;
    float acc[8][4];
#pragma unroll
    for (int i = 0; i < 8; ++i)
#pragma unroll
        for (int j = 0; j < 4; ++j) acc[i][j] = 0.f;
    for (int ks = 0; ks < 128; ks += 64) {
        __syncthreads();
        for (int i = t; i < 64 * 128; i += 256) {
            int kk = i & 63, r = i >> 6;
            int n = row0 + r;
            GT[kk][r] = (n < Nn) ? G[(size_t)n * 128 + ks + kk] : 0.f;
        }
        __syncthreads();
        for (int kk = 0; kk < 64; ++kk) {
            const float4 h0 = *(const float4*)&GT[kk][r0];
            const float4 h1 = *(const float4*)&GT[kk][r0 + 4];
            const float4 w = *(const float4*)&WT[ks + kk][c0];
            float hv[8] = {h0.x, h0.y, h0.z, h0.w, h1.x, h1.y, h1.z, h1.w};
            float wv2[4] = {w.x, w.y, w.z, w.w};
#pragma unroll
            for (int i = 0; i < 8; ++i)
#pragma unroll
                for (int j = 0; j < 4; ++j) acc[i][j] = fmaf(hv[i], wv2[j], acc[i][j]);
        }
    }
#pragma unroll
    for (int i = 0; i < 8; ++i) {
        int n = row0 + r0 + i;
        if (n >= Nn) continue;
        float* dst = X + (size_t)n * 64 + c0;
        float4 xv = *(float4*)dst;
        xv.x += acc[i][0] + BS[c0];
        xv.y += acc[i][1] + BS[c0 + 1];
        xv.z += acc[i][2] + BS[c0 + 2];
        xv.w += acc[i][3] + BS[c0 + 3];
        *(float4*)dst = xv;
        if (dopool) {
            int bI = batch[n];
            float vs[4] = {xv.x, xv.y, xv.z, xv.w};
#pragma unroll
            for (int jj = 0; jj < 4; ++jj) {
                u32 u = __float_as_uint(vs[jj]);
                u32 key = (u >> 31) ? ~u : (u | 0x80000000u);
                atomicMax(&pkeys[bI * 64 + c0 + jj], key);
            }
        }
    }
}

// ---------------- head: relu(pooled@Wo1+bo1)@Wo2+bo2, L2-normalize ----------------
__global__ __launch_bounds__(128) void k_head(const u32* __restrict__ pkeys,
    const float* __restrict__ Wo1, const float* __restrict__ bo1,
    const float* __restrict__ Wo2, const float* __restrict__ bo2,
    float* __restrict__ out)
{
    __shared__ float P[64];
    __shared__ float E1[128];
    __shared__ float wred[2];
    int b = blockIdx.x, t = threadIdx.x;
    if (t < 64) {
        u32 k = pkeys[b * 64 + t];
        float v = 0.f;
        if (k) v = (k >> 31) ? __uint_as_float(k ^ 0x80000000u) : __uint_as_float(~k);
        P[t] = v;
    }
    __syncthreads();
    float a = bo1[t];
#pragma unroll 8
    for (int k = 0; k < 64; ++k) a = fmaf(P[k], Wo1[k * 128 + t], a);
    E1[t] = fmaxf(a, 0.f);
    __syncthreads();
    float o = bo2[t];
#pragma unroll 8
    for (int k = 0; k < 128; ++k) o = fmaf(E1[k], Wo2[k * 128 + t], o);
    float ss = o * o;
#pragma unroll
    for (int off = 32; off; off >>= 1) ss += __shfl_xor(ss, off);
    if ((t & 63) == 0) wred[t >> 6] = ss;
    __syncthreads();
    float tot = wred[0] + wred[1];
    float nrm = fmaxf(sqrtf(tot), 1e-12f);
    out[b * 128 + t] = o / nrm;
}

// ---------------- launch ----------------
extern "C" void kernel_launch(void* const* d_in, const int* in_sizes, int n_in,
                              void* d_out, int out_size, void* d_ws, size_t ws_size,
                              hipStream_t stream)
{
    const float* x         = (const float*)d_in[0];
    const float* edge_attr = (const float*)d_in[1];
    const int* ei          = (const int*)d_in[2];
    const int* batch       = (const int*)d_in[3];
    const float* Win  = (const float*)d_in[4];
    const float* bin  = (const float*)d_in[5];
    const float* ln1g = (const float*)d_in[6];
    const float* ln1b = (const float*)d_in[7];
    const float* Wq   = (const float*)d_in[8];
    const float* bq   = (const float*)d_in[9];
    const float* Wk   = (const float*)d_in[10];
    const float* bk   = (const float*)d_in[11];
    const float* Wv   = (const float*)d_in[12];
    const float* bv   = (const float*)d_in[13];
    const float* We   = (const float*)d_in[14];
    const float* Wsk  = (const float*)d_in[15];
    const float* bsk  = (const float*)d_in[16];
    const float* Wbe  = (const float*)d_in[17];
    const float* ln2g = (const float*)d_in[18];
    const float* ln2b = (const float*)d_in[19];
    const float* W1   = (const float*)d_in[20];
    const float* b1   = (const float*)d_in[21];
    const float* W2   = (const float*)d_in[22];
    const float* b2   = (const float*)d_in[23];
    const float* Wo1  = (const float*)d_in[24];
    const float* bo1  = (const float*)d_in[25];
    const float* Wo2  = (const float*)d_in[26];
    const float* bo2  = (const float*)d_in[27];

    char* wsp = (char*)d_ws;
    size_t off = 0;
    auto alloc = [&](size_t bytes) { void* p = wsp + off; off = (off + bytes + 255) & ~(size_t)255; return p; };
    float*   X      = (float*)alloc((size_t)Nn * 64 * 4);
    float*   QX     = (float*)alloc((size_t)Nn * 128 * 4);
    u32*     KV     = (u32*)alloc((size_t)Nn * 64 * 4);
    float*   G      = (float*)alloc((size_t)Nn * 128 * 4);
    int*     rowptr = (int*)alloc((size_t)(Nn + 1) * 4);
    int*     deg    = (int*)alloc((size_t)Nn * 4);
    int*     cursor = (int*)alloc((size_t)Nn * 4);
    int*     colsrc = (int*)alloc((size_t)Ee * 4);
    float4*  ea4    = (float4*)alloc((size_t)Ee * 16);
    u32*     pkeys  = (u32*)alloc((size_t)Bb * 64 * 4);

    hipMemsetAsync(deg, 0, (size_t)Nn * 4, stream);
    hipMemsetAsync(cursor, 0, (size_t)Nn * 4, stream);
    hipMemsetAsync(pkeys, 0, (size_t)Bb * 64 * 4, stream);

    k_input_proj<<<12500, 256, 0, stream>>>(x, Win, bin, X);
    k_hist<<<(Ee + 255) / 256, 256, 0, stream>>>(ei, deg);
    k_scan<<<1, 1024, 0, stream>>>(deg, rowptr);
    k_scatter<<<(Ee + 255) / 256, 256, 0, stream>>>(ei, edge_attr, rowptr, cursor, colsrc, ea4);

    const int gb = (Nn + 127) / 128;  // 391
    for (int l = 0; l < 3; ++l) {
        k_ln_proj<<<dim3(gb, 2), 256, 0, stream>>>(X, QX, KV,
            Wq + l * 4096, Wk + l * 4096, Wv + l * 4096, Wsk + l * 4096,
            bq + l * 64, bk + l * 64, bv + l * 64, bsk + l * 64,
            ln1g + l * 64, ln1b + l * 64);
        k_edge<<<Nn / 4, 256, 0, stream>>>(QX, KV, X, rowptr, colsrc, ea4,
            We + l * 256, Wbe + l * 192);
        k_ln_ffn1<<<gb, 256, 0, stream>>>(X, G, W1 + l * 8192, b1 + l * 128,
            ln2g + l * 64, ln2b + l * 64);
        k_ffn2<<<gb, 256, 0, stream>>>(G, X, W2 + l * 8192, b2 + l * 64,
            batch, pkeys, (l == 2) ? 1 : 0);
    }
    k_head<<<Bb, 128, 0, stream>>>(pkeys, Wo1, bo1, Wo2, bo2, (float*)d_out);
}

// Round 4
// 631.352 us; speedup vs baseline: 1.6211x; 1.6117x over previous
//
#include <hip/hip_runtime.h>
#include <hip/hip_bf16.h>
#include <hip/hip_fp16.h>

#define Nn 50000
#define Ee 1000000
#define Bb 512
#define NG 3125   // 50000/16 node-row groups (exact)

typedef unsigned short u16;
typedef unsigned int u32;
typedef _Float16 f16;
typedef _Float16 f16x8 __attribute__((ext_vector_type(8)));
typedef float f32x4 __attribute__((ext_vector_type(4)));

__device__ __forceinline__ u16 f2h(float f) { return __half_as_ushort(__float2half(f)); }
__device__ __forceinline__ float h2f_lo(u32 kv) { return __half2float(__ushort_as_half((u16)(kv & 0xffff))); }
__device__ __forceinline__ float h2f_hi(u32 kv) { return __half2float(__ushort_as_half((u16)(kv >> 16))); }

// ---------------- input projection: X = x @ W_in + b_in ----------------
__global__ __launch_bounds__(256) void k_input_proj(const float* __restrict__ x,
    const float* __restrict__ Win, const float* __restrict__ bin, float* __restrict__ X)
{
    __shared__ float W[8][64];
    __shared__ float bsh[64];
    int t = threadIdx.x;
    if (t < 64) bsh[t] = bin[t];
    for (int i = t; i < 512; i += 256) W[i >> 6][i & 63] = Win[i];
    __syncthreads();
    int gid = blockIdx.x * 256 + t;
    int n = gid >> 6, c = gid & 63;
    const float* xr = x + n * 8;
    float acc = bsh[c];
#pragma unroll
    for (int k = 0; k < 8; ++k) acc = fmaf(xr[k], W[k][c], acc);
    X[gid] = acc;
}

// ---------------- CSR build ----------------
__global__ __launch_bounds__(256) void k_hist(const int* __restrict__ ei, int* __restrict__ deg)
{
    int e = blockIdx.x * 256 + threadIdx.x;
    if (e < Ee) atomicAdd(&deg[ei[Ee + e]], 1);
}

__global__ __launch_bounds__(1024) void k_scan(const int* __restrict__ deg, int* __restrict__ rowptr)
{
    __shared__ int wsum[16];
    const int C = 49;
    int t = threadIdx.x, lane = t & 63, w = t >> 6;
    int start = t * C;
    int s = 0;
#pragma unroll 7
    for (int i = 0; i < C; ++i) {
        int idx = start + i;
        if (idx < Nn) s += deg[idx];
    }
    int sc = s;
#pragma unroll
    for (int off = 1; off < 64; off <<= 1) {
        int u = __shfl_up(sc, off);
        if (lane >= off) sc += u;
    }
    if (lane == 63) wsum[w] = sc;
    __syncthreads();
    if (t == 0) {
        int a = 0;
#pragma unroll
        for (int i = 0; i < 16; ++i) { a += wsum[i]; wsum[i] = a; }
    }
    __syncthreads();
    int run = sc - s + (w ? wsum[w - 1] : 0);
    for (int i = 0; i < C; ++i) {
        int idx = start + i;
        if (idx < Nn) { run += deg[idx]; rowptr[idx + 1] = run; }
    }
    if (t == 0) rowptr[0] = 0;
}

__global__ __launch_bounds__(256) void k_scatter(const int* __restrict__ ei, const float* __restrict__ eattr,
    const int* __restrict__ rowptr, int* __restrict__ cursor, int* __restrict__ colsrc,
    float4* __restrict__ ea4)
{
    int e = blockIdx.x * 256 + threadIdx.x;
    if (e >= Ee) return;
    int d = ei[Ee + e];
    int pos = rowptr[d] + atomicAdd(&cursor[d], 1);
    colsrc[pos] = ei[e];
    ea4[pos] = *(const float4*)(eattr + (size_t)e * 4);
}

// ---------------- MFMA helpers ----------------
// A fragment (16x32, f16): lane holds A[lane&15][(lane>>4)*8 + i], k-window chosen by s (0/1 -> k+=32s)
// B fragment (32xN,  f16): lane holds B[k0 + i][col], k0 = s*32 + (lane>>4)*8, col = tile*16 + (lane&15)
// D (16x16, f32x4):        lane holds D[(lane>>4)*4 + j][lane&15]
__device__ __forceinline__ f16x8 load_bfrag(const float* __restrict__ W, int NC, int col, int k0)
{
    f16x8 b;
    const float* wp = W + (size_t)k0 * NC + col;
#pragma unroll
    for (int i = 0; i < 8; ++i) b[i] = (f16)wp[i * NC];
    return b;
}

// LayerNorm over 64 channels of 16 rows, emitted as two A fragments (k 0..31, 32..63)
__device__ __forceinline__ void build_ln_a(const float* __restrict__ X, int n0, int lane,
    const float* __restrict__ lng, const float* __restrict__ lnb, f16x8* a)
{
    const int r = lane & 15, c = lane >> 4;
    const float* xp = X + (size_t)(n0 + r) * 64 + c * 8;
    float4 x0 = *(const float4*)(xp);
    float4 x1 = *(const float4*)(xp + 4);
    float4 x2 = *(const float4*)(xp + 32);
    float4 x3 = *(const float4*)(xp + 36);
    float xs[16] = {x0.x, x0.y, x0.z, x0.w, x1.x, x1.y, x1.z, x1.w,
                    x2.x, x2.y, x2.z, x2.w, x3.x, x3.y, x3.z, x3.w};
    float s = 0.f, s2 = 0.f;
#pragma unroll
    for (int i = 0; i < 16; ++i) { s += xs[i]; s2 = fmaf(xs[i], xs[i], s2); }
    s += __shfl_xor(s, 16);  s += __shfl_xor(s, 32);
    s2 += __shfl_xor(s2, 16); s2 += __shfl_xor(s2, 32);
    float mu = s * 0.015625f;
    float var = s2 * 0.015625f - mu * mu;
    float rstd = rsqrtf(fmaxf(var, 0.f) + 1e-5f);
    const float* gp = lng + c * 8;
    const float* bp = lnb + c * 8;
    float4 g0 = *(const float4*)(gp),      g1 = *(const float4*)(gp + 4);
    float4 g2 = *(const float4*)(gp + 32), g3 = *(const float4*)(gp + 36);
    float4 b0 = *(const float4*)(bp),      b1 = *(const float4*)(bp + 4);
    float4 b2 = *(const float4*)(bp + 32), b3 = *(const float4*)(bp + 36);
    float gs[16] = {g0.x, g0.y, g0.z, g0.w, g1.x, g1.y, g1.z, g1.w,
                    g2.x, g2.y, g2.z, g2.w, g3.x, g3.y, g3.z, g3.w};
    float bs[16] = {b0.x, b0.y, b0.z, b0.w, b1.x, b1.y, b1.z, b1.w,
                    b2.x, b2.y, b2.z, b2.w, b3.x, b3.y, b3.z, b3.w};
#pragma unroll
    for (int i = 0; i < 16; ++i) {
        float h = (xs[i] - mu) * rstd * gs[i] + bs[i];
        a[i >> 3][i & 7] = (f16)h;
    }
}

// ---------------- LN1 + K,V projection -> packed f16 KV ----------------
__global__ __launch_bounds__(256) void k_proj_kv(const float* __restrict__ X, u32* __restrict__ KV,
    const float* __restrict__ Wk, const float* __restrict__ Wv,
    const float* __restrict__ bk, const float* __restrict__ bv,
    const float* __restrict__ lng, const float* __restrict__ lnb)
{
    const int lane = threadIdx.x & 63;
    const int wid = (blockIdx.x * 256 + threadIdx.x) >> 6;
    const int nw = gridDim.x * 4;
    const int ch_base = lane & 15;
    const int k0b = (lane >> 4) * 8;
    f16x8 bw[8][2];
#pragma unroll
    for (int t = 0; t < 4; ++t)
#pragma unroll
        for (int s = 0; s < 2; ++s) {
            bw[t][s]     = load_bfrag(Wk, 64, t * 16 + ch_base, s * 32 + k0b);
            bw[t + 4][s] = load_bfrag(Wv, 64, t * 16 + ch_base, s * 32 + k0b);
        }
    float bk_l[4], bv_l[4];
#pragma unroll
    for (int t = 0; t < 4; ++t) { bk_l[t] = bk[t * 16 + ch_base]; bv_l[t] = bv[t * 16 + ch_base]; }
    for (int g = wid; g < NG; g += nw) {
        int n0 = g * 16;
        f16x8 a[2];
        build_ln_a(X, n0, lane, lng, lnb, a);
        f32x4 acc[8];
#pragma unroll
        for (int t = 0; t < 8; ++t) { acc[t][0] = 0.f; acc[t][1] = 0.f; acc[t][2] = 0.f; acc[t][3] = 0.f; }
#pragma unroll
        for (int t = 0; t < 8; ++t)
#pragma unroll
            for (int s = 0; s < 2; ++s)
                acc[t] = __builtin_amdgcn_mfma_f32_16x16x32_f16(a[s], bw[t][s], acc[t], 0, 0, 0);
        int rbase = n0 + (lane >> 4) * 4;
#pragma unroll
        for (int t = 0; t < 4; ++t) {
            int ch = t * 16 + ch_base;
#pragma unroll
            for (int j = 0; j < 4; ++j) {
                u32 lo = f2h(acc[t][j] + bk_l[t]);
                u32 hi = f2h(acc[t + 4][j] + bv_l[t]);
                KV[(size_t)(rbase + j) * 64 + ch] = (hi << 16) | lo;
            }
        }
    }
}

// ---------------- LN1 + Q,Skip projection -> QX f32 [q(64)|xr(64)] ----------------
__global__ __launch_bounds__(256) void k_proj_qs(const float* __restrict__ X, float* __restrict__ QX,
    const float* __restrict__ Wq, const float* __restrict__ Ws,
    const float* __restrict__ bq, const float* __restrict__ bs_,
    const float* __restrict__ lng, const float* __restrict__ lnb)
{
    const int lane = threadIdx.x & 63;
    const int wid = (blockIdx.x * 256 + threadIdx.x) >> 6;
    const int nw = gridDim.x * 4;
    const int ch_base = lane & 15;
    const int k0b = (lane >> 4) * 8;
    f16x8 bw[8][2];
#pragma unroll
    for (int t = 0; t < 4; ++t)
#pragma unroll
        for (int s = 0; s < 2; ++s) {
            bw[t][s]     = load_bfrag(Wq, 64, t * 16 + ch_base, s * 32 + k0b);
            bw[t + 4][s] = load_bfrag(Ws, 64, t * 16 + ch_base, s * 32 + k0b);
        }
    float bq_l[4], bs_l[4];
#pragma unroll
    for (int t = 0; t < 4; ++t) { bq_l[t] = bq[t * 16 + ch_base]; bs_l[t] = bs_[t * 16 + ch_base]; }
    for (int g = wid; g < NG; g += nw) {
        int n0 = g * 16;
        f16x8 a[2];
        build_ln_a(X, n0, lane, lng, lnb, a);
        f32x4 acc[8];
#pragma unroll
        for (int t = 0; t < 8; ++t) { acc[t][0] = 0.f; acc[t][1] = 0.f; acc[t][2] = 0.f; acc[t][3] = 0.f; }
#pragma unroll
        for (int t = 0; t < 8; ++t)
#pragma unroll
            for (int s = 0; s < 2; ++s)
                acc[t] = __builtin_amdgcn_mfma_f32_16x16x32_f16(a[s], bw[t][s], acc[t], 0, 0, 0);
        int rbase = n0 + (lane >> 4) * 4;
#pragma unroll
        for (int t = 0; t < 4; ++t) {
            int ch = t * 16 + ch_base;
#pragma unroll
            for (int j = 0; j < 4; ++j) {
                float* dst = QX + (size_t)(rbase + j) * 128;
                dst[ch] = acc[t][j] + bq_l[t];
                dst[64 + ch] = acc[t + 4][j] + bs_l[t];
            }
        }
    }
}

// ---------------- edge attention: one wave/node, 2-way interleaved online softmax ----------------
__global__ __launch_bounds__(256) void k_edge(
    const float* __restrict__ QX, const u32* __restrict__ KV, float* __restrict__ X,
    const int* __restrict__ rowptr, const int* __restrict__ colsrc,
    const float4* __restrict__ ea4,
    const float* __restrict__ We, const float* __restrict__ Wbeta)
{
    int lane = threadIdx.x & 63;
    int node = blockIdx.x * 4 + (threadIdx.x >> 6);
    if (node >= Nn) return;
    float we0 = We[lane], we1 = We[64 + lane];
    float we2 = We[128 + lane], we3 = We[192 + lane];
    float wbA = Wbeta[lane] + Wbeta[128 + lane];
    float wbB = Wbeta[64 + lane] - Wbeta[128 + lane];
    const float* qrow = QX + (size_t)node * 128;
    float q = qrow[lane];
    float xr = qrow[64 + lane];
    int jb = rowptr[node], je = rowptr[node + 1];
    float m0 = -1e30f, l0 = 0.f, a0 = 0.f;
    float m1 = -1e30f, l1 = 0.f, a1 = 0.f;
    int j = jb;
    for (; j + 1 < je; j += 2) {
        int s0 = colsrc[j], s1 = colsrc[j + 1];
        float4 eb0 = ea4[j], eb1 = ea4[j + 1];
        u32 kv0 = KV[(size_t)s0 * 64 + lane];
        u32 kv1 = KV[(size_t)s1 * 64 + lane];
        float e0 = we0 * eb0.x;
        e0 = fmaf(we1, eb0.y, e0); e0 = fmaf(we2, eb0.z, e0); e0 = fmaf(we3, eb0.w, e0);
        float e1 = we0 * eb1.x;
        e1 = fmaf(we1, eb1.y, e1); e1 = fmaf(we2, eb1.z, e1); e1 = fmaf(we3, eb1.w, e1);
        float ke0 = h2f_lo(kv0) + e0, ve0 = h2f_hi(kv0) + e0;
        float ke1 = h2f_lo(kv1) + e1, ve1 = h2f_hi(kv1) + e1;
        float p0 = q * ke0, p1 = q * ke1;
        p0 += __shfl_xor(p0, 1); p1 += __shfl_xor(p1, 1);
        p0 += __shfl_xor(p0, 2); p1 += __shfl_xor(p1, 2);
        p0 += __shfl_xor(p0, 4); p1 += __shfl_xor(p1, 4);
        p0 += __shfl_xor(p0, 8); p1 += __shfl_xor(p1, 8);
        float sA = p0 * 0.25f, sB = p1 * 0.25f;
        float mnA = fmaxf(m0, sA), mnB = fmaxf(m1, sB);
        float cA = __expf(m0 - mnA), cB = __expf(m1 - mnB);
        float pA = __expf(sA - mnA), pB = __expf(sB - mnB);
        l0 = l0 * cA + pA;            l1 = l1 * cB + pB;
        a0 = a0 * cA + pA * ve0;      a1 = a1 * cB + pB * ve1;
        m0 = mnA;                     m1 = mnB;
    }
    if (j < je) {
        int s0 = colsrc[j];
        float4 eb0 = ea4[j];
        u32 kv0 = KV[(size_t)s0 * 64 + lane];
        float e0 = we0 * eb0.x;
        e0 = fmaf(we1, eb0.y, e0); e0 = fmaf(we2, eb0.z, e0); e0 = fmaf(we3, eb0.w, e0);
        float ke0 = h2f_lo(kv0) + e0, ve0 = h2f_hi(kv0) + e0;
        float p0 = q * ke0;
        p0 += __shfl_xor(p0, 1);
        p0 += __shfl_xor(p0, 2);
        p0 += __shfl_xor(p0, 4);
        p0 += __shfl_xor(p0, 8);
        float sA = p0 * 0.25f;
        float mnA = fmaxf(m0, sA);
        float cA = __expf(m0 - mnA);
        float pA = __expf(sA - mnA);
        l0 = l0 * cA + pA;
        a0 = a0 * cA + pA * ve0;
        m0 = mnA;
    }
    float mn = fmaxf(m0, m1);
    float c0 = __expf(m0 - mn), c1 = __expf(m1 - mn);
    float lsum = l0 * c0 + l1 * c1;
    float acc = a0 * c0 + a1 * c1;
    float outv = acc / (lsum + 1e-16f);
    float tb = outv * wbA + xr * wbB;
#pragma unroll
    for (int off = 32; off; off >>= 1) tb += __shfl_xor(tb, off);
    float beta = 1.f / (1.f + __expf(-tb));
    float res = beta * xr + (1.f - beta) * outv;
    X[(size_t)node * 64 + lane] += res;
}

// ---------------- LN2 + FFN1 (64->128) + GELU -> G f16 ----------------
__global__ __launch_bounds__(256) void k_ffn1_m(const float* __restrict__ X, u16* __restrict__ G16,
    const float* __restrict__ W1, const float* __restrict__ b1,
    const float* __restrict__ lng, const float* __restrict__ lnb)
{
    const int lane = threadIdx.x & 63;
    const int wid = (blockIdx.x * 256 + threadIdx.x) >> 6;
    const int nw = gridDim.x * 4;
    const int ch_base = lane & 15;
    const int k0b = (lane >> 4) * 8;
    f16x8 bw[8][2];
#pragma unroll
    for (int t = 0; t < 8; ++t)
#pragma unroll
        for (int s = 0; s < 2; ++s)
            bw[t][s] = load_bfrag(W1, 128, t * 16 + ch_base, s * 32 + k0b);
    float b1_l[8];
#pragma unroll
    for (int t = 0; t < 8; ++t) b1_l[t] = b1[t * 16 + ch_base];
    for (int g = wid; g < NG; g += nw) {
        int n0 = g * 16;
        f16x8 a[2];
        build_ln_a(X, n0, lane, lng, lnb, a);
        f32x4 acc[8];
#pragma unroll
        for (int t = 0; t < 8; ++t) { acc[t][0] = 0.f; acc[t][1] = 0.f; acc[t][2] = 0.f; acc[t][3] = 0.f; }
#pragma unroll
        for (int t = 0; t < 8; ++t)
#pragma unroll
            for (int s = 0; s < 2; ++s)
                acc[t] = __builtin_amdgcn_mfma_f32_16x16x32_f16(a[s], bw[t][s], acc[t], 0, 0, 0);
        int rbase = n0 + (lane >> 4) * 4;
#pragma unroll
        for (int t = 0; t < 8; ++t) {
            int ch = t * 16 + ch_base;
#pragma unroll
            for (int j = 0; j < 4; ++j) {
                float v = acc[t][j] + b1_l[t];
                float o = 0.5f * v * (1.f + erff(v * 0.7071067811865476f));
                G16[(size_t)(rbase + j) * 128 + ch] = f2h(o);
            }
        }
    }
}

// ---------------- FFN2 (128->64) + residual into X (+ fused pool on last layer) ----------------
__global__ __launch_bounds__(256) void k_ffn2_m(const u16* __restrict__ G16, float* __restrict__ X,
    const float* __restrict__ W2, const float* __restrict__ b2,
    const int* __restrict__ batch, u32* __restrict__ pkeys, int dopool)
{
    const int lane = threadIdx.x & 63;
    const int wid = (blockIdx.x * 256 + threadIdx.x) >> 6;
    const int nw = gridDim.x * 4;
    const int ch_base = lane & 15;
    const int k0b = (lane >> 4) * 8;
    f16x8 bw[4][4];
#pragma unroll
    for (int t = 0; t < 4; ++t)
#pragma unroll
        for (int s = 0; s < 4; ++s)
            bw[t][s] = load_bfrag(W2, 64, t * 16 + ch_base, s * 32 + k0b);
    float b2_l[4];
#pragma unroll
    for (int t = 0; t < 4; ++t) b2_l[t] = b2[t * 16 + ch_base];
    for (int g = wid; g < NG; g += nw) {
        int n0 = g * 16;
        const u16* gp = G16 + (size_t)(n0 + ch_base) * 128 + k0b;
        f16x8 a0 = *(const f16x8*)(gp);
        f16x8 a1 = *(const f16x8*)(gp + 32);
        f16x8 a2 = *(const f16x8*)(gp + 64);
        f16x8 a3 = *(const f16x8*)(gp + 96);
        f32x4 acc[4];
#pragma unroll
        for (int t = 0; t < 4; ++t) { acc[t][0] = 0.f; acc[t][1] = 0.f; acc[t][2] = 0.f; acc[t][3] = 0.f; }
#pragma unroll
        for (int t = 0; t < 4; ++t) {
            acc[t] = __builtin_amdgcn_mfma_f32_16x16x32_f16(a0, bw[t][0], acc[t], 0, 0, 0);
            acc[t] = __builtin_amdgcn_mfma_f32_16x16x32_f16(a1, bw[t][1], acc[t], 0, 0, 0);
            acc[t] = __builtin_amdgcn_mfma_f32_16x16x32_f16(a2, bw[t][2], acc[t], 0, 0, 0);
            acc[t] = __builtin_amdgcn_mfma_f32_16x16x32_f16(a3, bw[t][3], acc[t], 0, 0, 0);
        }
        int rbase = n0 + (lane >> 4) * 4;
#pragma unroll
        for (int t = 0; t < 4; ++t) {
            int ch = t * 16 + ch_base;
#pragma unroll
            for (int j = 0; j < 4; ++j) {
                int n = rbase + j;
                float* dst = X + (size_t)n * 64 + ch;
                float v = *dst + acc[t][j] + b2_l[t];
                *dst = v;
                if (dopool) {
                    u32 u = __float_as_uint(v);
                    u32 key = (u >> 31) ? ~u : (u | 0x80000000u);
                    atomicMax(&pkeys[batch[n] * 64 + ch], key);
                }
            }
        }
    }
}

// ---------------- head: relu(pooled@Wo1+bo1)@Wo2+bo2, L2-normalize ----------------
__global__ __launch_bounds__(128) void k_head(const u32* __restrict__ pkeys,
    const float* __restrict__ Wo1, const float* __restrict__ bo1,
    const float* __restrict__ Wo2, const float* __restrict__ bo2,
    float* __restrict__ out)
{
    __shared__ float P[64];
    __shared__ float E1[128];
    __shared__ float wred[2];
    int b = blockIdx.x, t = threadIdx.x;
    if (t < 64) {
        u32 k = pkeys[b * 64 + t];
        float v = 0.f;
        if (k) v = (k >> 31) ? __uint_as_float(k ^ 0x80000000u) : __uint_as_float(~k);
        P[t] = v;
    }
    __syncthreads();
    float a = bo1[t];
#pragma unroll 8
    for (int k = 0; k < 64; ++k) a = fmaf(P[k], Wo1[k * 128 + t], a);
    E1[t] = fmaxf(a, 0.f);
    __syncthreads();
    float o = bo2[t];
#pragma unroll 8
    for (int k = 0; k < 128; ++k) o = fmaf(E1[k], Wo2[k * 128 + t], o);
    float ss = o * o;
#pragma unroll
    for (int off = 32; off; off >>= 1) ss += __shfl_xor(ss, off);
    if ((t & 63) == 0) wred[t >> 6] = ss;
    __syncthreads();
    float tot = wred[0] + wred[1];
    float nrm = fmaxf(sqrtf(tot), 1e-12f);
    out[b * 128 + t] = o / nrm;
}

// ---------------- launch ----------------
extern "C" void kernel_launch(void* const* d_in, const int* in_sizes, int n_in,
                              void* d_out, int out_size, void* d_ws, size_t ws_size,
                              hipStream_t stream)
{
    const float* x         = (const float*)d_in[0];
    const float* edge_attr = (const float*)d_in[1];
    const int* ei          = (const int*)d_in[2];
    const int* batch       = (const int*)d_in[3];
    const float* Win  = (const float*)d_in[4];
    const float* bin  = (const float*)d_in[5];
    const float* ln1g = (const float*)d_in[6];
    const float* ln1b = (const float*)d_in[7];
    const float* Wq   = (const float*)d_in[8];
    const float* bq   = (const float*)d_in[9];
    const float* Wk   = (const float*)d_in[10];
    const float* bk   = (const float*)d_in[11];
    const float* Wv   = (const float*)d_in[12];
    const float* bv   = (const float*)d_in[13];
    const float* We   = (const float*)d_in[14];
    const float* Wsk  = (const float*)d_in[15];
    const float* bsk  = (const float*)d_in[16];
    const float* Wbe  = (const float*)d_in[17];
    const float* ln2g = (const float*)d_in[18];
    const float* ln2b = (const float*)d_in[19];
    const float* W1   = (const float*)d_in[20];
    const float* b1   = (const float*)d_in[21];
    const float* W2   = (const float*)d_in[22];
    const float* b2   = (const float*)d_in[23];
    const float* Wo1  = (const float*)d_in[24];
    const float* bo1  = (const float*)d_in[25];
    const float* Wo2  = (const float*)d_in[26];
    const float* bo2  = (const float*)d_in[27];

    char* wsp = (char*)d_ws;
    size_t off = 0;
    auto alloc = [&](size_t bytes) { void* p = wsp + off; off = (off + bytes + 255) & ~(size_t)255; return p; };
    float*   X      = (float*)alloc((size_t)Nn * 64 * 4);
    float*   QX     = (float*)alloc((size_t)Nn * 128 * 4);
    u32*     KV     = (u32*)alloc((size_t)Nn * 64 * 4);
    u16*     G16    = (u16*)alloc((size_t)Nn * 128 * 2);
    int*     rowptr = (int*)alloc((size_t)(Nn + 1) * 4);
    int*     deg    = (int*)alloc((size_t)Nn * 4);
    int*     cursor = (int*)alloc((size_t)Nn * 4);
    int*     colsrc = (int*)alloc((size_t)Ee * 4);
    float4*  ea4    = (float4*)alloc((size_t)Ee * 16);
    u32*     pkeys  = (u32*)alloc((size_t)Bb * 64 * 4);

    hipMemsetAsync(deg, 0, (size_t)Nn * 4, stream);
    hipMemsetAsync(cursor, 0, (size_t)Nn * 4, stream);
    hipMemsetAsync(pkeys, 0, (size_t)Bb * 64 * 4, stream);

    k_input_proj<<<12500, 256, 0, stream>>>(x, Win, bin, X);
    k_hist<<<(Ee + 255) / 256, 256, 0, stream>>>(ei, deg);
    k_scan<<<1, 1024, 0, stream>>>(deg, rowptr);
    k_scatter<<<(Ee + 255) / 256, 256, 0, stream>>>(ei, edge_attr, rowptr, cursor, colsrc, ea4);

    const int GB = 512;  // grid for MFMA kernels: 2 blocks/CU, ~1.5 groups/wave
    for (int l = 0; l < 3; ++l) {
        k_proj_kv<<<GB, 256, 0, stream>>>(X, KV, Wk + l * 4096, Wv + l * 4096,
            bk + l * 64, bv + l * 64, ln1g + l * 64, ln1b + l * 64);
        k_proj_qs<<<GB, 256, 0, stream>>>(X, QX, Wq + l * 4096, Wsk + l * 4096,
            bq + l * 64, bsk + l * 64, ln1g + l * 64, ln1b + l * 64);
        k_edge<<<Nn / 4, 256, 0, stream>>>(QX, KV, X, rowptr, colsrc, ea4,
            We + l * 256, Wbe + l * 192);
        k_ffn1_m<<<GB, 256, 0, stream>>>(X, G16, W1 + l * 8192, b1 + l * 128,
            ln2g + l * 64, ln2b + l * 64);
        k_ffn2_m<<<GB, 256, 0, stream>>>(G16, X, W2 + l * 8192, b2 + l * 64,
            batch, pkeys, (l == 2) ? 1 : 0);
    }
    k_head<<<Bb, 128, 0, stream>>>(pkeys, Wo1, bo1, Wo2, bo2, (float*)d_out);
}

// Round 5
// 525.783 us; speedup vs baseline: 1.9466x; 1.2008x over previous
//
#include <hip/hip_runtime.h>
#include <hip/hip_bf16.h>
#include <hip/hip_fp16.h>

#define Nn 50000
#define Ee 1000000
#define Bb 512
#define NG 3125   // 50000/16 node-row groups (exact)
#define SCB 196   // ceil(50000/256) scan blocks

typedef unsigned short u16;
typedef unsigned int u32;
typedef _Float16 f16;
typedef _Float16 f16x8 __attribute__((ext_vector_type(8)));
typedef float f32x4 __attribute__((ext_vector_type(4)));

__device__ __forceinline__ u16 f2h(float f) { return __half_as_ushort(__float2half(f)); }
__device__ __forceinline__ float h2f_lo(u32 kv) { return __half2float(__ushort_as_half((u16)(kv & 0xffff))); }
__device__ __forceinline__ float h2f_hi(u32 kv) { return __half2float(__ushort_as_half((u16)(kv >> 16))); }

// ---------------- input projection: X = x @ W_in + b_in ----------------
__global__ __launch_bounds__(256) void k_input_proj(const float* __restrict__ x,
    const float* __restrict__ Win, const float* __restrict__ bin, float* __restrict__ X)
{
    __shared__ float W[8][64];
    __shared__ float bsh[64];
    int t = threadIdx.x;
    if (t < 64) bsh[t] = bin[t];
    for (int i = t; i < 512; i += 256) W[i >> 6][i & 63] = Win[i];
    __syncthreads();
    int gid = blockIdx.x * 256 + t;
    int n = gid >> 6, c = gid & 63;
    const float* xr = x + n * 8;
    float acc = bsh[c];
#pragma unroll
    for (int k = 0; k < 8; ++k) acc = fmaf(xr[k], W[k][c], acc);
    X[gid] = acc;
}

// ---------------- CSR build ----------------
__global__ __launch_bounds__(256) void k_hist(const int* __restrict__ ei, int* __restrict__ deg)
{
    int e = blockIdx.x * 256 + threadIdx.x;
    if (e < Ee) atomicAdd(&deg[ei[Ee + e]], 1);
}

// phase 1: per-block sums
__global__ __launch_bounds__(256) void k_part(const int* __restrict__ deg, int* __restrict__ psum)
{
    __shared__ int ws[4];
    int b = blockIdx.x, t = threadIdx.x;
    int idx = b * 256 + t;
    int v = (idx < Nn) ? deg[idx] : 0;
    int r = v;
#pragma unroll
    for (int off = 32; off; off >>= 1) r += __shfl_xor(r, off);
    if ((t & 63) == 0) ws[t >> 6] = r;
    __syncthreads();
    if (t == 0) psum[b] = ws[0] + ws[1] + ws[2] + ws[3];
}

// phase 2: exclusive scan of SCB partials (1 block, 256 threads)
__global__ __launch_bounds__(256) void k_scanp(const int* __restrict__ psum, int* __restrict__ poff)
{
    __shared__ int ws[4];
    int t = threadIdx.x, lane = t & 63, w = t >> 6;
    int v = (t < SCB) ? psum[t] : 0;
    int s = v;
#pragma unroll
    for (int off = 1; off < 64; off <<= 1) {
        int u = __shfl_up(s, off);
        if (lane >= off) s += u;
    }
    if (lane == 63) ws[w] = s;
    __syncthreads();
    if (t == 0) { int a = 0; for (int i = 0; i < 4; ++i) { a += ws[i]; ws[i] = a; } }
    __syncthreads();
    int incl = s + (w ? ws[w - 1] : 0);
    if (t < SCB) poff[t] = incl - v;
}

// phase 3: block-local scan + offset -> rowptr
__global__ __launch_bounds__(256) void k_apply(const int* __restrict__ deg, const int* __restrict__ poff,
    int* __restrict__ rowptr)
{
    __shared__ int ws[4];
    int b = blockIdx.x, t = threadIdx.x, lane = t & 63, w = t >> 6;
    int idx = b * 256 + t;
    int v = (idx < Nn) ? deg[idx] : 0;
    int s = v;
#pragma unroll
    for (int off = 1; off < 64; off <<= 1) {
        int u = __shfl_up(s, off);
        if (lane >= off) s += u;
    }
    if (lane == 63) ws[w] = s;
    __syncthreads();
    if (t == 0) { int a = 0; for (int i = 0; i < 4; ++i) { a += ws[i]; ws[i] = a; } }
    __syncthreads();
    int incl = s + (w ? ws[w - 1] : 0) + poff[b];
    if (idx < Nn) rowptr[idx + 1] = incl;
    if (b == 0 && t == 0) rowptr[0] = 0;
}

__global__ __launch_bounds__(256) void k_scatter(const int* __restrict__ ei, const float* __restrict__ eattr,
    const int* __restrict__ rowptr, int* __restrict__ cursor, int* __restrict__ colsrc,
    float4* __restrict__ ea4)
{
    int e = blockIdx.x * 256 + threadIdx.x;
    if (e >= Ee) return;
    int d = ei[Ee + e];
    int pos = rowptr[d] + atomicAdd(&cursor[d], 1);
    colsrc[pos] = ei[e];
    ea4[pos] = *(const float4*)(eattr + (size_t)e * 4);
}

// ---------------- MFMA helpers ----------------
__device__ __forceinline__ f16x8 load_bfrag(const float* __restrict__ W, int NC, int col, int k0)
{
    f16x8 b;
    const float* wp = W + (size_t)k0 * NC + col;
#pragma unroll
    for (int i = 0; i < 8; ++i) b[i] = (f16)wp[i * NC];
    return b;
}

__device__ __forceinline__ void build_ln_a(const float* __restrict__ X, int n0, int lane,
    const float* __restrict__ lng, const float* __restrict__ lnb, f16x8* a)
{
    const int r = lane & 15, c = lane >> 4;
    const float* xp = X + (size_t)(n0 + r) * 64 + c * 8;
    float4 x0 = *(const float4*)(xp);
    float4 x1 = *(const float4*)(xp + 4);
    float4 x2 = *(const float4*)(xp + 32);
    float4 x3 = *(const float4*)(xp + 36);
    float xs[16] = {x0.x, x0.y, x0.z, x0.w, x1.x, x1.y, x1.z, x1.w,
                    x2.x, x2.y, x2.z, x2.w, x3.x, x3.y, x3.z, x3.w};
    float s = 0.f, s2 = 0.f;
#pragma unroll
    for (int i = 0; i < 16; ++i) { s += xs[i]; s2 = fmaf(xs[i], xs[i], s2); }
    s += __shfl_xor(s, 16);  s += __shfl_xor(s, 32);
    s2 += __shfl_xor(s2, 16); s2 += __shfl_xor(s2, 32);
    float mu = s * 0.015625f;
    float var = s2 * 0.015625f - mu * mu;
    float rstd = rsqrtf(fmaxf(var, 0.f) + 1e-5f);
    const float* gp = lng + c * 8;
    const float* bp = lnb + c * 8;
    float4 g0 = *(const float4*)(gp),      g1 = *(const float4*)(gp + 4);
    float4 g2 = *(const float4*)(gp + 32), g3 = *(const float4*)(gp + 36);
    float4 b0 = *(const float4*)(bp),      b1 = *(const float4*)(bp + 4);
    float4 b2 = *(const float4*)(bp + 32), b3 = *(const float4*)(bp + 36);
    float gs[16] = {g0.x, g0.y, g0.z, g0.w, g1.x, g1.y, g1.z, g1.w,
                    g2.x, g2.y, g2.z, g2.w, g3.x, g3.y, g3.z, g3.w};
    float bs[16] = {b0.x, b0.y, b0.z, b0.w, b1.x, b1.y, b1.z, b1.w,
                    b2.x, b2.y, b2.z, b2.w, b3.x, b3.y, b3.z, b3.w};
#pragma unroll
    for (int i = 0; i < 16; ++i) {
        float h = (xs[i] - mu) * rstd * gs[i] + bs[i];
        a[i >> 3][i & 7] = (f16)h;
    }
}

// ---------------- LN1 + K,V projection -> packed f16 KV ----------------
__global__ __launch_bounds__(256) void k_proj_kv(const float* __restrict__ X, u32* __restrict__ KV,
    const float* __restrict__ Wk, const float* __restrict__ Wv,
    const float* __restrict__ bk, const float* __restrict__ bv,
    const float* __restrict__ lng, const float* __restrict__ lnb)
{
    const int lane = threadIdx.x & 63;
    const int wid = (blockIdx.x * 256 + threadIdx.x) >> 6;
    const int nw = gridDim.x * 4;
    const int ch_base = lane & 15;
    const int k0b = (lane >> 4) * 8;
    f16x8 bw[8][2];
#pragma unroll
    for (int t = 0; t < 4; ++t)
#pragma unroll
        for (int s = 0; s < 2; ++s) {
            bw[t][s]     = load_bfrag(Wk, 64, t * 16 + ch_base, s * 32 + k0b);
            bw[t + 4][s] = load_bfrag(Wv, 64, t * 16 + ch_base, s * 32 + k0b);
        }
    float bk_l[4], bv_l[4];
#pragma unroll
    for (int t = 0; t < 4; ++t) { bk_l[t] = bk[t * 16 + ch_base]; bv_l[t] = bv[t * 16 + ch_base]; }
    for (int g = wid; g < NG; g += nw) {
        int n0 = g * 16;
        f16x8 a[2];
        build_ln_a(X, n0, lane, lng, lnb, a);
        f32x4 acc[8];
#pragma unroll
        for (int t = 0; t < 8; ++t) { acc[t][0] = 0.f; acc[t][1] = 0.f; acc[t][2] = 0.f; acc[t][3] = 0.f; }
#pragma unroll
        for (int t = 0; t < 8; ++t)
#pragma unroll
            for (int s = 0; s < 2; ++s)
                acc[t] = __builtin_amdgcn_mfma_f32_16x16x32_f16(a[s], bw[t][s], acc[t], 0, 0, 0);
        int rbase = n0 + (lane >> 4) * 4;
#pragma unroll
        for (int t = 0; t < 4; ++t) {
            int ch = t * 16 + ch_base;
#pragma unroll
            for (int j = 0; j < 4; ++j) {
                u32 lo = f2h(acc[t][j] + bk_l[t]);
                u32 hi = f2h(acc[t + 4][j] + bv_l[t]);
                KV[(size_t)(rbase + j) * 64 + ch] = (hi << 16) | lo;
            }
        }
    }
}

// ---------------- LN1 + Q,Skip projection -> QX f32 [q(64)|xr(64)] ----------------
__global__ __launch_bounds__(256) void k_proj_qs(const float* __restrict__ X, float* __restrict__ QX,
    const float* __restrict__ Wq, const float* __restrict__ Ws,
    const float* __restrict__ bq, const float* __restrict__ bs_,
    const float* __restrict__ lng, const float* __restrict__ lnb)
{
    const int lane = threadIdx.x & 63;
    const int wid = (blockIdx.x * 256 + threadIdx.x) >> 6;
    const int nw = gridDim.x * 4;
    const int ch_base = lane & 15;
    const int k0b = (lane >> 4) * 8;
    f16x8 bw[8][2];
#pragma unroll
    for (int t = 0; t < 4; ++t)
#pragma unroll
        for (int s = 0; s < 2; ++s) {
            bw[t][s]     = load_bfrag(Wq, 64, t * 16 + ch_base, s * 32 + k0b);
            bw[t + 4][s] = load_bfrag(Ws, 64, t * 16 + ch_base, s * 32 + k0b);
        }
    float bq_l[4], bs_l[4];
#pragma unroll
    for (int t = 0; t < 4; ++t) { bq_l[t] = bq[t * 16 + ch_base]; bs_l[t] = bs_[t * 16 + ch_base]; }
    for (int g = wid; g < NG; g += nw) {
        int n0 = g * 16;
        f16x8 a[2];
        build_ln_a(X, n0, lane, lng, lnb, a);
        f32x4 acc[8];
#pragma unroll
        for (int t = 0; t < 8; ++t) { acc[t][0] = 0.f; acc[t][1] = 0.f; acc[t][2] = 0.f; acc[t][3] = 0.f; }
#pragma unroll
        for (int t = 0; t < 8; ++t)
#pragma unroll
            for (int s = 0; s < 2; ++s)
                acc[t] = __builtin_amdgcn_mfma_f32_16x16x32_f16(a[s], bw[t][s], acc[t], 0, 0, 0);
        int rbase = n0 + (lane >> 4) * 4;
#pragma unroll
        for (int t = 0; t < 4; ++t) {
            int ch = t * 16 + ch_base;
#pragma unroll
            for (int j = 0; j < 4; ++j) {
                float* dst = QX + (size_t)(rbase + j) * 128;
                dst[ch] = acc[t][j] + bq_l[t];
                dst[64 + ch] = acc[t + 4][t < 4 ? j : j] + bs_l[t];
            }
        }
    }
}

// ---------------- edge attention: one wave/node, 4-way interleaved online softmax ----------------
__global__ __launch_bounds__(256) void k_edge(
    const float* __restrict__ QX, const u32* __restrict__ KV, float* __restrict__ X,
    const int* __restrict__ rowptr, const int* __restrict__ colsrc,
    const float4* __restrict__ ea4,
    const float* __restrict__ We, const float* __restrict__ Wbeta)
{
    int lane = threadIdx.x & 63;
    int node = blockIdx.x * 4 + (threadIdx.x >> 6);
    if (node >= Nn) return;
    float we0 = We[lane], we1 = We[64 + lane];
    float we2 = We[128 + lane], we3 = We[192 + lane];
    float wbA = Wbeta[lane] + Wbeta[128 + lane];
    float wbB = Wbeta[64 + lane] - Wbeta[128 + lane];
    const float* qrow = QX + (size_t)node * 128;
    float q = qrow[lane];
    float xr = qrow[64 + lane];
    int jb = rowptr[node], je = rowptr[node + 1];
    float m[4], l[4], a[4];
#pragma unroll
    for (int c = 0; c < 4; ++c) { m[c] = -1e30f; l[c] = 0.f; a[c] = 0.f; }
    int j = jb;
    for (; j + 3 < je; j += 4) {
        int src[4]; float4 eb[4]; u32 kv[4];
#pragma unroll
        for (int c = 0; c < 4; ++c) src[c] = colsrc[j + c];
#pragma unroll
        for (int c = 0; c < 4; ++c) kv[c] = KV[(size_t)src[c] * 64 + lane];
#pragma unroll
        for (int c = 0; c < 4; ++c) eb[c] = ea4[j + c];
        float p[4], ve[4];
#pragma unroll
        for (int c = 0; c < 4; ++c) {
            float e = we0 * eb[c].x;
            e = fmaf(we1, eb[c].y, e); e = fmaf(we2, eb[c].z, e); e = fmaf(we3, eb[c].w, e);
            float ke = h2f_lo(kv[c]) + e;
            ve[c] = h2f_hi(kv[c]) + e;
            p[c] = q * ke;
        }
#pragma unroll
        for (int c = 0; c < 4; ++c) {
            p[c] += __shfl_xor(p[c], 1);
            p[c] += __shfl_xor(p[c], 2);
            p[c] += __shfl_xor(p[c], 4);
            p[c] += __shfl_xor(p[c], 8);
        }
#pragma unroll
        for (int c = 0; c < 4; ++c) {
            float s = p[c] * 0.25f;
            float mn = fmaxf(m[c], s);
            float cr = __expf(m[c] - mn);
            float pe = __expf(s - mn);
            l[c] = l[c] * cr + pe;
            a[c] = a[c] * cr + pe * ve[c];
            m[c] = mn;
        }
    }
    for (; j < je; ++j) {
        int s0 = colsrc[j];
        float4 eb0 = ea4[j];
        u32 kv0 = KV[(size_t)s0 * 64 + lane];
        float e0 = we0 * eb0.x;
        e0 = fmaf(we1, eb0.y, e0); e0 = fmaf(we2, eb0.z, e0); e0 = fmaf(we3, eb0.w, e0);
        float ke0 = h2f_lo(kv0) + e0, ve0 = h2f_hi(kv0) + e0;
        float p0 = q * ke0;
        p0 += __shfl_xor(p0, 1);
        p0 += __shfl_xor(p0, 2);
        p0 += __shfl_xor(p0, 4);
        p0 += __shfl_xor(p0, 8);
        float sA = p0 * 0.25f;
        float mn = fmaxf(m[0], sA);
        float cr = __expf(m[0] - mn);
        float pe = __expf(sA - mn);
        l[0] = l[0] * cr + pe;
        a[0] = a[0] * cr + pe * ve0;
        m[0] = mn;
    }
    float mn = fmaxf(fmaxf(m[0], m[1]), fmaxf(m[2], m[3]));
    float lsum = 0.f, acc = 0.f;
#pragma unroll
    for (int c = 0; c < 4; ++c) {
        float cr = __expf(m[c] - mn);
        lsum += l[c] * cr;
        acc += a[c] * cr;
    }
    float outv = acc / (lsum + 1e-16f);
    float tb = outv * wbA + xr * wbB;
#pragma unroll
    for (int off = 32; off; off >>= 1) tb += __shfl_xor(tb, off);
    float beta = 1.f / (1.f + __expf(-tb));
    float res = beta * xr + (1.f - beta) * outv;
    X[(size_t)node * 64 + lane] += res;
}

// ---------------- LN2 + FFN1 (64->128) + GELU -> G f16 ----------------
__global__ __launch_bounds__(256) void k_ffn1_m(const float* __restrict__ X, u16* __restrict__ G16,
    const float* __restrict__ W1, const float* __restrict__ b1,
    const float* __restrict__ lng, const float* __restrict__ lnb)
{
    const int lane = threadIdx.x & 63;
    const int wid = (blockIdx.x * 256 + threadIdx.x) >> 6;
    const int nw = gridDim.x * 4;
    const int ch_base = lane & 15;
    const int k0b = (lane >> 4) * 8;
    f16x8 bw[8][2];
#pragma unroll
    for (int t = 0; t < 8; ++t)
#pragma unroll
        for (int s = 0; s < 2; ++s)
            bw[t][s] = load_bfrag(W1, 128, t * 16 + ch_base, s * 32 + k0b);
    float b1_l[8];
#pragma unroll
    for (int t = 0; t < 8; ++t) b1_l[t] = b1[t * 16 + ch_base];
    for (int g = wid; g < NG; g += nw) {
        int n0 = g * 16;
        f16x8 a[2];
        build_ln_a(X, n0, lane, lng, lnb, a);
        f32x4 acc[8];
#pragma unroll
        for (int t = 0; t < 8; ++t) { acc[t][0] = 0.f; acc[t][1] = 0.f; acc[t][2] = 0.f; acc[t][3] = 0.f; }
#pragma unroll
        for (int t = 0; t < 8; ++t)
#pragma unroll
            for (int s = 0; s < 2; ++s)
                acc[t] = __builtin_amdgcn_mfma_f32_16x16x32_f16(a[s], bw[t][s], acc[t], 0, 0, 0);
        int rbase = n0 + (lane >> 4) * 4;
#pragma unroll
        for (int t = 0; t < 8; ++t) {
            int ch = t * 16 + ch_base;
#pragma unroll
            for (int j = 0; j < 4; ++j) {
                float v = acc[t][j] + b1_l[t];
                float o = 0.5f * v * (1.f + erff(v * 0.7071067811865476f));
                G16[(size_t)(rbase + j) * 128 + ch] = f2h(o);
            }
        }
    }
}

// ---------------- FFN2 (128->64) + residual into X (+ fused pool on last layer) ----------------
__global__ __launch_bounds__(256) void k_ffn2_m(const u16* __restrict__ G16, float* __restrict__ X,
    const float* __restrict__ W2, const float* __restrict__ b2,
    const int* __restrict__ batch, u32* __restrict__ pkeys, int dopool)
{
    const int lane = threadIdx.x & 63;
    const int wid = (blockIdx.x * 256 + threadIdx.x) >> 6;
    const int nw = gridDim.x * 4;
    const int ch_base = lane & 15;
    const int k0b = (lane >> 4) * 8;
    f16x8 bw[4][4];
#pragma unroll
    for (int t = 0; t < 4; ++t)
#pragma unroll
        for (int s = 0; s < 4; ++s)
            bw[t][s] = load_bfrag(W2, 64, t * 16 + ch_base, s * 32 + k0b);
    float b2_l[4];
#pragma unroll
    for (int t = 0; t < 4; ++t) b2_l[t] = b2[t * 16 + ch_base];
    for (int g = wid; g < NG; g += nw) {
        int n0 = g * 16;
        const u16* gp = G16 + (size_t)(n0 + ch_base) * 128 + k0b;
        f16x8 a0 = *(const f16x8*)(gp);
        f16x8 a1 = *(const f16x8*)(gp + 32);
        f16x8 a2 = *(const f16x8*)(gp + 64);
        f16x8 a3 = *(const f16x8*)(gp + 96);
        f32x4 acc[4];
#pragma unroll
        for (int t = 0; t < 4; ++t) { acc[t][0] = 0.f; acc[t][1] = 0.f; acc[t][2] = 0.f; acc[t][3] = 0.f; }
#pragma unroll
        for (int t = 0; t < 4; ++t) {
            acc[t] = __builtin_amdgcn_mfma_f32_16x16x32_f16(a0, bw[t][0], acc[t], 0, 0, 0);
            acc[t] = __builtin_amdgcn_mfma_f32_16x16x32_f16(a1, bw[t][1], acc[t], 0, 0, 0);
            acc[t] = __builtin_amdgcn_mfma_f32_16x16x32_f16(a2, bw[t][2], acc[t], 0, 0, 0);
            acc[t] = __builtin_amdgcn_mfma_f32_16x16x32_f16(a3, bw[t][3], acc[t], 0, 0, 0);
        }
        int rbase = n0 + (lane >> 4) * 4;
#pragma unroll
        for (int t = 0; t < 4; ++t) {
            int ch = t * 16 + ch_base;
#pragma unroll
            for (int j = 0; j < 4; ++j) {
                int n = rbase + j;
                float* dst = X + (size_t)n * 64 + ch;
                float v = *dst + acc[t][j] + b2_l[t];
                *dst = v;
                if (dopool) {
                    u32 u = __float_as_uint(v);
                    u32 key = (u >> 31) ? ~u : (u | 0x80000000u);
                    atomicMax(&pkeys[batch[n] * 64 + ch], key);
                }
            }
        }
    }
}

// ---------------- head: relu(pooled@Wo1+bo1)@Wo2+bo2, L2-normalize ----------------
__global__ __launch_bounds__(128) void k_head(const u32* __restrict__ pkeys,
    const float* __restrict__ Wo1, const float* __restrict__ bo1,
    const float* __restrict__ Wo2, const float* __restrict__ bo2,
    float* __restrict__ out)
{
    __shared__ float P[64];
    __shared__ float E1[128];
    __shared__ float wred[2];
    int b = blockIdx.x, t = threadIdx.x;
    if (t < 64) {
        u32 k = pkeys[b * 64 + t];
        float v = 0.f;
        if (k) v = (k >> 31) ? __uint_as_float(k ^ 0x80000000u) : __uint_as_float(~k);
        P[t] = v;
    }
    __syncthreads();
    float a = bo1[t];
#pragma unroll 8
    for (int k = 0; k < 64; ++k) a = fmaf(P[k], Wo1[k * 128 + t], a);
    E1[t] = fmaxf(a, 0.f);
    __syncthreads();
    float o = bo2[t];
#pragma unroll 8
    for (int k = 0; k < 128; ++k) o = fmaf(E1[k], Wo2[k * 128 + t], o);
    float ss = o * o;
#pragma unroll
    for (int off = 32; off; off >>= 1) ss += __shfl_xor(ss, off);
    if ((t & 63) == 0) wred[t >> 6] = ss;
    __syncthreads();
    float tot = wred[0] + wred[1];
    float nrm = fmaxf(sqrtf(tot), 1e-12f);
    out[b * 128 + t] = o / nrm;
}

// ---------------- launch ----------------
extern "C" void kernel_launch(void* const* d_in, const int* in_sizes, int n_in,
                              void* d_out, int out_size, void* d_ws, size_t ws_size,
                              hipStream_t stream)
{
    const float* x         = (const float*)d_in[0];
    const float* edge_attr = (const float*)d_in[1];
    const int* ei          = (const int*)d_in[2];
    const int* batch       = (const int*)d_in[3];
    const float* Win  = (const float*)d_in[4];
    const float* bin  = (const float*)d_in[5];
    const float* ln1g = (const float*)d_in[6];
    const float* ln1b = (const float*)d_in[7];
    const float* Wq   = (const float*)d_in[8];
    const float* bq   = (const float*)d_in[9];
    const float* Wk   = (const float*)d_in[10];
    const float* bk   = (const float*)d_in[11];
    const float* Wv   = (const float*)d_in[12];
    const float* bv   = (const float*)d_in[13];
    const float* We   = (const float*)d_in[14];
    const float* Wsk  = (const float*)d_in[15];
    const float* bsk  = (const float*)d_in[16];
    const float* Wbe  = (const float*)d_in[17];
    const float* ln2g = (const float*)d_in[18];
    const float* ln2b = (const float*)d_in[19];
    const float* W1   = (const float*)d_in[20];
    const float* b1   = (const float*)d_in[21];
    const float* W2   = (const float*)d_in[22];
    const float* b2   = (const float*)d_in[23];
    const float* Wo1  = (const float*)d_in[24];
    const float* bo1  = (const float*)d_in[25];
    const float* Wo2  = (const float*)d_in[26];
    const float* bo2  = (const float*)d_in[27];

    char* wsp = (char*)d_ws;
    size_t off = 0;
    auto alloc = [&](size_t bytes) { void* p = wsp + off; off = (off + bytes + 255) & ~(size_t)255; return p; };
    float*   X      = (float*)alloc((size_t)Nn * 64 * 4);
    float*   QX     = (float*)alloc((size_t)Nn * 128 * 4);
    u32*     KV     = (u32*)alloc((size_t)Nn * 64 * 4);
    u16*     G16    = (u16*)alloc((size_t)Nn * 128 * 2);
    int*     rowptr = (int*)alloc((size_t)(Nn + 1) * 4);
    int*     deg    = (int*)alloc((size_t)Nn * 4);
    int*     cursor = (int*)alloc((size_t)Nn * 4);
    int*     psum   = (int*)alloc((size_t)SCB * 4);
    int*     poff   = (int*)alloc((size_t)SCB * 4);
    int*     colsrc = (int*)alloc((size_t)Ee * 4);
    float4*  ea4    = (float4*)alloc((size_t)Ee * 16);
    u32*     pkeys  = (u32*)alloc((size_t)Bb * 64 * 4);

    hipMemsetAsync(deg, 0, (size_t)Nn * 4, stream);
    hipMemsetAsync(cursor, 0, (size_t)Nn * 4, stream);
    hipMemsetAsync(pkeys, 0, (size_t)Bb * 64 * 4, stream);

    k_input_proj<<<12500, 256, 0, stream>>>(x, Win, bin, X);
    k_hist<<<(Ee + 255) / 256, 256, 0, stream>>>(ei, deg);
    k_part<<<SCB, 256, 0, stream>>>(deg, psum);
    k_scanp<<<1, 256, 0, stream>>>(psum, poff);
    k_apply<<<SCB, 256, 0, stream>>>(deg, poff, rowptr);
    k_scatter<<<(Ee + 255) / 256, 256, 0, stream>>>(ei, edge_attr, rowptr, cursor, colsrc, ea4);

    const int GB = 512;
    for (int l = 0; l < 3; ++l) {
        k_proj_kv<<<GB, 256, 0, stream>>>(X, KV, Wk + l * 4096, Wv + l * 4096,
            bk + l * 64, bv + l * 64, ln1g + l * 64, ln1b + l * 64);
        k_proj_qs<<<GB, 256, 0, stream>>>(X, QX, Wq + l * 4096, Wsk + l * 4096,
            bq + l * 64, bsk + l * 64, ln1g + l * 64, ln1b + l * 64);
        k_edge<<<Nn / 4, 256, 0, stream>>>(QX, KV, X, rowptr, colsrc, ea4,
            We + l * 256, Wbe + l * 192);
        k_ffn1_m<<<GB, 256, 0, stream>>>(X, G16, W1 + l * 8192, b1 + l * 128,
            ln2g + l * 64, ln2b + l * 64);
        k_ffn2_m<<<GB, 256, 0, stream>>>(G16, X, W2 + l * 8192, b2 + l * 64,
            batch, pkeys, (l == 2) ? 1 : 0);
    }
    k_head<<<Bb, 128, 0, stream>>>(pkeys, Wo1, bo1, Wo2, bo2, (float*)d_out);
}

// Round 6
// 479.663 us; speedup vs baseline: 2.1338x; 1.0962x over previous
//
#include <hip/hip_runtime.h>
#include <hip/hip_bf16.h>
#include <hip/hip_fp16.h>

#define Nn 50000
#define Ee 1000000
#define Bb 512
#define NG 3125   // 50000/16 node-row groups (exact)
#define SCB 196   // ceil(50000/256) scan blocks

typedef unsigned short u16;
typedef unsigned int u32;
typedef _Float16 f16;
typedef _Float16 f16x8 __attribute__((ext_vector_type(8)));
typedef float f32x4 __attribute__((ext_vector_type(4)));

__device__ __forceinline__ u16 f2h(float f) { return __half_as_ushort(__float2half(f)); }
__device__ __forceinline__ float h2f_lo(u32 kv) { return __half2float(__ushort_as_half((u16)(kv & 0xffff))); }
__device__ __forceinline__ float h2f_hi(u32 kv) { return __half2float(__ushort_as_half((u16)(kv >> 16))); }

// 2^x in one VALU op
__device__ __forceinline__ float fexp2(float x) {
    float r;
    asm("v_exp_f32 %0, %1" : "=v"(r) : "v"(x));
    return r;
}

// butterfly sum over each 16-lane group (one head) via DPP: masks xor1,xor2,xor7,xor15 (rank 4)
__device__ __forceinline__ float red16(float x) {
    int t;
    t = __builtin_amdgcn_update_dpp(0, __float_as_int(x), 0xB1, 0xF, 0xF, true);   // quad_perm [1,0,3,2]
    x += __int_as_float(t);
    t = __builtin_amdgcn_update_dpp(0, __float_as_int(x), 0x4E, 0xF, 0xF, true);   // quad_perm [2,3,0,1]
    x += __int_as_float(t);
    t = __builtin_amdgcn_update_dpp(0, __float_as_int(x), 0x141, 0xF, 0xF, true);  // row_half_mirror (xor7)
    x += __int_as_float(t);
    t = __builtin_amdgcn_update_dpp(0, __float_as_int(x), 0x140, 0xF, 0xF, true);  // row_mirror (xor15)
    x += __int_as_float(t);
    return x;
}

// ---------------- input projection: X = x @ W_in + b_in ----------------
__global__ __launch_bounds__(256) void k_input_proj(const float* __restrict__ x,
    const float* __restrict__ Win, const float* __restrict__ bin, float* __restrict__ X)
{
    __shared__ float W[8][64];
    __shared__ float bsh[64];
    int t = threadIdx.x;
    if (t < 64) bsh[t] = bin[t];
    for (int i = t; i < 512; i += 256) W[i >> 6][i & 63] = Win[i];
    __syncthreads();
    int gid = blockIdx.x * 256 + t;
    int n = gid >> 6, c = gid & 63;
    const float* xr = x + n * 8;
    float acc = bsh[c];
#pragma unroll
    for (int k = 0; k < 8; ++k) acc = fmaf(xr[k], W[k][c], acc);
    X[gid] = acc;
}

// ---------------- CSR build ----------------
__global__ __launch_bounds__(256) void k_hist(const int* __restrict__ ei, int* __restrict__ deg)
{
    int e = blockIdx.x * 256 + threadIdx.x;
    if (e < Ee) atomicAdd(&deg[ei[Ee + e]], 1);
}

__global__ __launch_bounds__(256) void k_part(const int* __restrict__ deg, int* __restrict__ psum)
{
    __shared__ int ws[4];
    int b = blockIdx.x, t = threadIdx.x;
    int idx = b * 256 + t;
    int v = (idx < Nn) ? deg[idx] : 0;
    int r = v;
#pragma unroll
    for (int off = 32; off; off >>= 1) r += __shfl_xor(r, off);
    if ((t & 63) == 0) ws[t >> 6] = r;
    __syncthreads();
    if (t == 0) psum[b] = ws[0] + ws[1] + ws[2] + ws[3];
}

__global__ __launch_bounds__(256) void k_scanp(const int* __restrict__ psum, int* __restrict__ poff)
{
    __shared__ int ws[4];
    int t = threadIdx.x, lane = t & 63, w = t >> 6;
    int v = (t < SCB) ? psum[t] : 0;
    int s = v;
#pragma unroll
    for (int off = 1; off < 64; off <<= 1) {
        int u = __shfl_up(s, off);
        if (lane >= off) s += u;
    }
    if (lane == 63) ws[w] = s;
    __syncthreads();
    if (t == 0) { int a = 0; for (int i = 0; i < 4; ++i) { a += ws[i]; ws[i] = a; } }
    __syncthreads();
    int incl = s + (w ? ws[w - 1] : 0);
    if (t < SCB) poff[t] = incl - v;
}

__global__ __launch_bounds__(256) void k_apply(const int* __restrict__ deg, const int* __restrict__ poff,
    int* __restrict__ rowptr)
{
    __shared__ int ws[4];
    int b = blockIdx.x, t = threadIdx.x, lane = t & 63, w = t >> 6;
    int idx = b * 256 + t;
    int v = (idx < Nn) ? deg[idx] : 0;
    int s = v;
#pragma unroll
    for (int off = 1; off < 64; off <<= 1) {
        int u = __shfl_up(s, off);
        if (lane >= off) s += u;
    }
    if (lane == 63) ws[w] = s;
    __syncthreads();
    if (t == 0) { int a = 0; for (int i = 0; i < 4; ++i) { a += ws[i]; ws[i] = a; } }
    __syncthreads();
    int incl = s + (w ? ws[w - 1] : 0) + poff[b];
    if (idx < Nn) rowptr[idx + 1] = incl;
    if (b == 0 && t == 0) rowptr[0] = 0;
}

__global__ __launch_bounds__(256) void k_scatter(const int* __restrict__ ei, const float* __restrict__ eattr,
    const int* __restrict__ rowptr, int* __restrict__ cursor, int* __restrict__ colsrc,
    float4* __restrict__ ea4)
{
    int e = blockIdx.x * 256 + threadIdx.x;
    if (e >= Ee) return;
    int d = ei[Ee + e];
    int pos = rowptr[d] + atomicAdd(&cursor[d], 1);
    colsrc[pos] = ei[e];
    ea4[pos] = *(const float4*)(eattr + (size_t)e * 4);
}

// ---------------- MFMA helpers ----------------
__device__ __forceinline__ f16x8 load_bfrag(const float* __restrict__ W, int NC, int col, int k0)
{
    f16x8 b;
    const float* wp = W + (size_t)k0 * NC + col;
#pragma unroll
    for (int i = 0; i < 8; ++i) b[i] = (f16)wp[i * NC];
    return b;
}

__device__ __forceinline__ void build_ln_a(const float* __restrict__ X, int n0, int lane,
    const float* __restrict__ lng, const float* __restrict__ lnb, f16x8* a)
{
    const int r = lane & 15, c = lane >> 4;
    const float* xp = X + (size_t)(n0 + r) * 64 + c * 8;
    float4 x0 = *(const float4*)(xp);
    float4 x1 = *(const float4*)(xp + 4);
    float4 x2 = *(const float4*)(xp + 32);
    float4 x3 = *(const float4*)(xp + 36);
    float xs[16] = {x0.x, x0.y, x0.z, x0.w, x1.x, x1.y, x1.z, x1.w,
                    x2.x, x2.y, x2.z, x2.w, x3.x, x3.y, x3.z, x3.w};
    float s = 0.f, s2 = 0.f;
#pragma unroll
    for (int i = 0; i < 16; ++i) { s += xs[i]; s2 = fmaf(xs[i], xs[i], s2); }
    s += __shfl_xor(s, 16);  s += __shfl_xor(s, 32);
    s2 += __shfl_xor(s2, 16); s2 += __shfl_xor(s2, 32);
    float mu = s * 0.015625f;
    float var = s2 * 0.015625f - mu * mu;
    float rstd = rsqrtf(fmaxf(var, 0.f) + 1e-5f);
    const float* gp = lng + c * 8;
    const float* bp = lnb + c * 8;
    float4 g0 = *(const float4*)(gp),      g1 = *(const float4*)(gp + 4);
    float4 g2 = *(const float4*)(gp + 32), g3 = *(const float4*)(gp + 36);
    float4 b0 = *(const float4*)(bp),      b1 = *(const float4*)(bp + 4);
    float4 b2 = *(const float4*)(bp + 32), b3 = *(const float4*)(bp + 36);
    float gs[16] = {g0.x, g0.y, g0.z, g0.w, g1.x, g1.y, g1.z, g1.w,
                    g2.x, g2.y, g2.z, g2.w, g3.x, g3.y, g3.z, g3.w};
    float bs[16] = {b0.x, b0.y, b0.z, b0.w, b1.x, b1.y, b1.z, b1.w,
                    b2.x, b2.y, b2.z, b2.w, b3.x, b3.y, b3.z, b3.w};
#pragma unroll
    for (int i = 0; i < 16; ++i) {
        float h = (xs[i] - mu) * rstd * gs[i] + bs[i];
        a[i >> 3][i & 7] = (f16)h;
    }
}

// ---------------- LN1 + K,V projection -> packed f16 KV ----------------
__global__ __launch_bounds__(256) void k_proj_kv(const float* __restrict__ X, u32* __restrict__ KV,
    const float* __restrict__ Wk, const float* __restrict__ Wv,
    const float* __restrict__ bk, const float* __restrict__ bv,
    const float* __restrict__ lng, const float* __restrict__ lnb)
{
    const int lane = threadIdx.x & 63;
    const int wid = (blockIdx.x * 256 + threadIdx.x) >> 6;
    const int nw = gridDim.x * 4;
    const int ch_base = lane & 15;
    const int k0b = (lane >> 4) * 8;
    f16x8 bw[8][2];
#pragma unroll
    for (int t = 0; t < 4; ++t)
#pragma unroll
        for (int s = 0; s < 2; ++s) {
            bw[t][s]     = load_bfrag(Wk, 64, t * 16 + ch_base, s * 32 + k0b);
            bw[t + 4][s] = load_bfrag(Wv, 64, t * 16 + ch_base, s * 32 + k0b);
        }
    float bk_l[4], bv_l[4];
#pragma unroll
    for (int t = 0; t < 4; ++t) { bk_l[t] = bk[t * 16 + ch_base]; bv_l[t] = bv[t * 16 + ch_base]; }
    for (int g = wid; g < NG; g += nw) {
        int n0 = g * 16;
        f16x8 a[2];
        build_ln_a(X, n0, lane, lng, lnb, a);
        f32x4 acc[8];
#pragma unroll
        for (int t = 0; t < 8; ++t) { acc[t][0] = 0.f; acc[t][1] = 0.f; acc[t][2] = 0.f; acc[t][3] = 0.f; }
#pragma unroll
        for (int t = 0; t < 8; ++t)
#pragma unroll
            for (int s = 0; s < 2; ++s)
                acc[t] = __builtin_amdgcn_mfma_f32_16x16x32_f16(a[s], bw[t][s], acc[t], 0, 0, 0);
        int rbase = n0 + (lane >> 4) * 4;
#pragma unroll
        for (int t = 0; t < 4; ++t) {
            int ch = t * 16 + ch_base;
#pragma unroll
            for (int j = 0; j < 4; ++j) {
                u32 lo = f2h(acc[t][j] + bk_l[t]);
                u32 hi = f2h(acc[t + 4][j] + bv_l[t]);
                KV[(size_t)(rbase + j) * 64 + ch] = (hi << 16) | lo;
            }
        }
    }
}

// ---------------- LN1 + Q,Skip projection -> QX f32 [q(64)|xr(64)] ----------------
__global__ __launch_bounds__(256) void k_proj_qs(const float* __restrict__ X, float* __restrict__ QX,
    const float* __restrict__ Wq, const float* __restrict__ Ws,
    const float* __restrict__ bq, const float* __restrict__ bs_,
    const float* __restrict__ lng, const float* __restrict__ lnb)
{
    const int lane = threadIdx.x & 63;
    const int wid = (blockIdx.x * 256 + threadIdx.x) >> 6;
    const int nw = gridDim.x * 4;
    const int ch_base = lane & 15;
    const int k0b = (lane >> 4) * 8;
    f16x8 bw[8][2];
#pragma unroll
    for (int t = 0; t < 4; ++t)
#pragma unroll
        for (int s = 0; s < 2; ++s) {
            bw[t][s]     = load_bfrag(Wq, 64, t * 16 + ch_base, s * 32 + k0b);
            bw[t + 4][s] = load_bfrag(Ws, 64, t * 16 + ch_base, s * 32 + k0b);
        }
    float bq_l[4], bs_l[4];
#pragma unroll
    for (int t = 0; t < 4; ++t) { bq_l[t] = bq[t * 16 + ch_base]; bs_l[t] = bs_[t * 16 + ch_base]; }
    for (int g = wid; g < NG; g += nw) {
        int n0 = g * 16;
        f16x8 a[2];
        build_ln_a(X, n0, lane, lng, lnb, a);
        f32x4 acc[8];
#pragma unroll
        for (int t = 0; t < 8; ++t) { acc[t][0] = 0.f; acc[t][1] = 0.f; acc[t][2] = 0.f; acc[t][3] = 0.f; }
#pragma unroll
        for (int t = 0; t < 8; ++t)
#pragma unroll
            for (int s = 0; s < 2; ++s)
                acc[t] = __builtin_amdgcn_mfma_f32_16x16x32_f16(a[s], bw[t][s], acc[t], 0, 0, 0);
        int rbase = n0 + (lane >> 4) * 4;
#pragma unroll
        for (int t = 0; t < 4; ++t) {
            int ch = t * 16 + ch_base;
#pragma unroll
            for (int j = 0; j < 4; ++j) {
                float* dst = QX + (size_t)(rbase + j) * 128;
                dst[ch] = acc[t][j] + bq_l[t];
                dst[64 + ch] = acc[t + 4][j] + bs_l[t];
            }
        }
    }
}

// ---------------- edge attention: one wave/node, no-max online softmax, DPP reduce ----------------
__global__ __launch_bounds__(256) void k_edge(
    const float* __restrict__ QX, const u32* __restrict__ KV, float* __restrict__ X,
    const int* __restrict__ rowptr, const int* __restrict__ colsrc,
    const float4* __restrict__ ea4,
    const float* __restrict__ We, const float* __restrict__ Wbeta)
{
    const float SCL = 0.25f * 1.4426950408889634f;  // 1/sqrt(D) * log2(e)
    int lane = threadIdx.x & 63;
    int node = blockIdx.x * 4 + (threadIdx.x >> 6);
    if (node >= Nn) return;
    float we0 = We[lane], we1 = We[64 + lane];
    float we2 = We[128 + lane], we3 = We[192 + lane];
    float wbA = Wbeta[lane] + Wbeta[128 + lane];
    float wbB = Wbeta[64 + lane] - Wbeta[128 + lane];
    const float* qrow = QX + (size_t)node * 128;
    float q = qrow[lane] * SCL;   // fold softmax scale + log2e into q
    float xr = qrow[64 + lane];
    int jb = rowptr[node], je = rowptr[node + 1];
    float l0 = 0.f, l1 = 0.f, a0 = 0.f, a1 = 0.f;
    int j = jb;
    for (; j + 3 < je; j += 4) {
        int src[4]; float4 eb[4]; u32 kv[4];
#pragma unroll
        for (int c = 0; c < 4; ++c) src[c] = colsrc[j + c];
#pragma unroll
        for (int c = 0; c < 4; ++c) kv[c] = KV[(src[c] << 6) | lane];
#pragma unroll
        for (int c = 0; c < 4; ++c) eb[c] = ea4[j + c];
        float pe[4], ve[4];
#pragma unroll
        for (int c = 0; c < 4; ++c) {
            float e = we0 * eb[c].x;
            e = fmaf(we1, eb[c].y, e); e = fmaf(we2, eb[c].z, e); e = fmaf(we3, eb[c].w, e);
            float ke = h2f_lo(kv[c]) + e;
            ve[c] = h2f_hi(kv[c]) + e;
            float p = red16(q * ke);
            pe[c] = fexp2(p);
        }
        l0 += pe[0]; l1 += pe[1];
        a0 = fmaf(pe[0], ve[0], a0); a1 = fmaf(pe[1], ve[1], a1);
        l0 += pe[2]; l1 += pe[3];
        a0 = fmaf(pe[2], ve[2], a0); a1 = fmaf(pe[3], ve[3], a1);
    }
    for (; j < je; ++j) {
        int s0 = colsrc[j];
        float4 eb0 = ea4[j];
        u32 kv0 = KV[(s0 << 6) | lane];
        float e0 = we0 * eb0.x;
        e0 = fmaf(we1, eb0.y, e0); e0 = fmaf(we2, eb0.z, e0); e0 = fmaf(we3, eb0.w, e0);
        float ke0 = h2f_lo(kv0) + e0, ve0 = h2f_hi(kv0) + e0;
        float p0 = red16(q * ke0);
        float pe0 = fexp2(p0);
        l0 += pe0;
        a0 = fmaf(pe0, ve0, a0);
    }
    float lsum = l0 + l1;
    float acc = a0 + a1;
    float outv = acc / (lsum + 1e-16f);
    float tb = outv * wbA + xr * wbB;
#pragma unroll
    for (int off = 32; off; off >>= 1) tb += __shfl_xor(tb, off);
    float beta = 1.f / (1.f + __expf(-tb));
    float res = beta * xr + (1.f - beta) * outv;
    X[(size_t)node * 64 + lane] += res;
}

// ---------------- LN2 + FFN1 (64->128) + GELU -> G f16 ----------------
__global__ __launch_bounds__(256) void k_ffn1_m(const float* __restrict__ X, u16* __restrict__ G16,
    const float* __restrict__ W1, const float* __restrict__ b1,
    const float* __restrict__ lng, const float* __restrict__ lnb)
{
    const int lane = threadIdx.x & 63;
    const int wid = (blockIdx.x * 256 + threadIdx.x) >> 6;
    const int nw = gridDim.x * 4;
    const int ch_base = lane & 15;
    const int k0b = (lane >> 4) * 8;
    f16x8 bw[8][2];
#pragma unroll
    for (int t = 0; t < 8; ++t)
#pragma unroll
        for (int s = 0; s < 2; ++s)
            bw[t][s] = load_bfrag(W1, 128, t * 16 + ch_base, s * 32 + k0b);
    float b1_l[8];
#pragma unroll
    for (int t = 0; t < 8; ++t) b1_l[t] = b1[t * 16 + ch_base];
    for (int g = wid; g < NG; g += nw) {
        int n0 = g * 16;
        f16x8 a[2];
        build_ln_a(X, n0, lane, lng, lnb, a);
        f32x4 acc[8];
#pragma unroll
        for (int t = 0; t < 8; ++t) { acc[t][0] = 0.f; acc[t][1] = 0.f; acc[t][2] = 0.f; acc[t][3] = 0.f; }
#pragma unroll
        for (int t = 0; t < 8; ++t)
#pragma unroll
            for (int s = 0; s < 2; ++s)
                acc[t] = __builtin_amdgcn_mfma_f32_16x16x32_f16(a[s], bw[t][s], acc[t], 0, 0, 0);
        int rbase = n0 + (lane >> 4) * 4;
#pragma unroll
        for (int t = 0; t < 8; ++t) {
            int ch = t * 16 + ch_base;
#pragma unroll
            for (int j = 0; j < 4; ++j) {
                float v = acc[t][j] + b1_l[t];
                float o = 0.5f * v * (1.f + erff(v * 0.7071067811865476f));
                G16[(size_t)(rbase + j) * 128 + ch] = f2h(o);
            }
        }
    }
}

// ---------------- FFN2 (128->64) + residual into X (+ fused pool on last layer) ----------------
__global__ __launch_bounds__(256) void k_ffn2_m(const u16* __restrict__ G16, float* __restrict__ X,
    const float* __restrict__ W2, const float* __restrict__ b2,
    const int* __restrict__ batch, u32* __restrict__ pkeys, int dopool)
{
    const int lane = threadIdx.x & 63;
    const int wid = (blockIdx.x * 256 + threadIdx.x) >> 6;
    const int nw = gridDim.x * 4;
    const int ch_base = lane & 15;
    const int k0b = (lane >> 4) * 8;
    f16x8 bw[4][4];
#pragma unroll
    for (int t = 0; t < 4; ++t)
#pragma unroll
        for (int s = 0; s < 4; ++s)
            bw[t][s] = load_bfrag(W2, 64, t * 16 + ch_base, s * 32 + k0b);
    float b2_l[4];
#pragma unroll
    for (int t = 0; t < 4; ++t) b2_l[t] = b2[t * 16 + ch_base];
    for (int g = wid; g < NG; g += nw) {
        int n0 = g * 16;
        const u16* gp = G16 + (size_t)(n0 + ch_base) * 128 + k0b;
        f16x8 a0 = *(const f16x8*)(gp);
        f16x8 a1 = *(const f16x8*)(gp + 32);
        f16x8 a2 = *(const f16x8*)(gp + 64);
        f16x8 a3 = *(const f16x8*)(gp + 96);
        f32x4 acc[4];
#pragma unroll
        for (int t = 0; t < 4; ++t) { acc[t][0] = 0.f; acc[t][1] = 0.f; acc[t][2] = 0.f; acc[t][3] = 0.f; }
#pragma unroll
        for (int t = 0; t < 4; ++t) {
            acc[t] = __builtin_amdgcn_mfma_f32_16x16x32_f16(a0, bw[t][0], acc[t], 0, 0, 0);
            acc[t] = __builtin_amdgcn_mfma_f32_16x16x32_f16(a1, bw[t][1], acc[t], 0, 0, 0);
            acc[t] = __builtin_amdgcn_mfma_f32_16x16x32_f16(a2, bw[t][2], acc[t], 0, 0, 0);
            acc[t] = __builtin_amdgcn_mfma_f32_16x16x32_f16(a3, bw[t][3], acc[t], 0, 0, 0);
        }
        int rbase = n0 + (lane >> 4) * 4;
#pragma unroll
        for (int t = 0; t < 4; ++t) {
            int ch = t * 16 + ch_base;
#pragma unroll
            for (int j = 0; j < 4; ++j) {
                int n = rbase + j;
                float* dst = X + (size_t)n * 64 + ch;
                float v = *dst + acc[t][j] + b2_l[t];
                *dst = v;
                if (dopool) {
                    u32 u = __float_as_uint(v);
                    u32 key = (u >> 31) ? ~u : (u | 0x80000000u);
                    atomicMax(&pkeys[batch[n] * 64 + ch], key);
                }
            }
        }
    }
}

// ---------------- head: relu(pooled@Wo1+bo1)@Wo2+bo2, L2-normalize ----------------
__global__ __launch_bounds__(128) void k_head(const u32* __restrict__ pkeys,
    const float* __restrict__ Wo1, const float* __restrict__ bo1,
    const float* __restrict__ Wo2, const float* __restrict__ bo2,
    float* __restrict__ out)
{
    __shared__ float P[64];
    __shared__ float E1[128];
    __shared__ float wred[2];
    int b = blockIdx.x, t = threadIdx.x;
    if (t < 64) {
        u32 k = pkeys[b * 64 + t];
        float v = 0.f;
        if (k) v = (k >> 31) ? __uint_as_float(k ^ 0x80000000u) : __uint_as_float(~k);
        P[t] = v;
    }
    __syncthreads();
    float a = bo1[t];
#pragma unroll 8
    for (int k = 0; k < 64; ++k) a = fmaf(P[k], Wo1[k * 128 + t], a);
    E1[t] = fmaxf(a, 0.f);
    __syncthreads();
    float o = bo2[t];
#pragma unroll 8
    for (int k = 0; k < 128; ++k) o = fmaf(E1[k], Wo2[k * 128 + t], o);
    float ss = o * o;
#pragma unroll
    for (int off = 32; off; off >>= 1) ss += __shfl_xor(ss, off);
    if ((t & 63) == 0) wred[t >> 6] = ss;
    __syncthreads();
    float tot = wred[0] + wred[1];
    float nrm = fmaxf(sqrtf(tot), 1e-12f);
    out[b * 128 + t] = o / nrm;
}

// ---------------- launch ----------------
extern "C" void kernel_launch(void* const* d_in, const int* in_sizes, int n_in,
                              void* d_out, int out_size, void* d_ws, size_t ws_size,
                              hipStream_t stream)
{
    const float* x         = (const float*)d_in[0];
    const float* edge_attr = (const float*)d_in[1];
    const int* ei          = (const int*)d_in[2];
    const int* batch       = (const int*)d_in[3];
    const float* Win  = (const float*)d_in[4];
    const float* bin  = (const float*)d_in[5];
    const float* ln1g = (const float*)d_in[6];
    const float* ln1b = (const float*)d_in[7];
    const float* Wq   = (const float*)d_in[8];
    const float* bq   = (const float*)d_in[9];
    const float* Wk   = (const float*)d_in[10];
    const float* bk   = (const float*)d_in[11];
    const float* Wv   = (const float*)d_in[12];
    const float* bv   = (const float*)d_in[13];
    const float* We   = (const float*)d_in[14];
    const float* Wsk  = (const float*)d_in[15];
    const float* bsk  = (const float*)d_in[16];
    const float* Wbe  = (const float*)d_in[17];
    const float* ln2g = (const float*)d_in[18];
    const float* ln2b = (const float*)d_in[19];
    const float* W1   = (const float*)d_in[20];
    const float* b1   = (const float*)d_in[21];
    const float* W2   = (const float*)d_in[22];
    const float* b2   = (const float*)d_in[23];
    const float* Wo1  = (const float*)d_in[24];
    const float* bo1  = (const float*)d_in[25];
    const float* Wo2  = (const float*)d_in[26];
    const float* bo2  = (const float*)d_in[27];

    char* wsp = (char*)d_ws;
    size_t off = 0;
    auto alloc = [&](size_t bytes) { void* p = wsp + off; off = (off + bytes + 255) & ~(size_t)255; return p; };
    float*   X      = (float*)alloc((size_t)Nn * 64 * 4);
    float*   QX     = (float*)alloc((size_t)Nn * 128 * 4);
    u32*     KV     = (u32*)alloc((size_t)Nn * 64 * 4);
    u16*     G16    = (u16*)alloc((size_t)Nn * 128 * 2);
    int*     rowptr = (int*)alloc((size_t)(Nn + 1) * 4);
    int*     deg    = (int*)alloc((size_t)Nn * 4);
    int*     cursor = (int*)alloc((size_t)Nn * 4);
    int*     psum   = (int*)alloc((size_t)SCB * 4);
    int*     poff   = (int*)alloc((size_t)SCB * 4);
    int*     colsrc = (int*)alloc((size_t)Ee * 4);
    float4*  ea4    = (float4*)alloc((size_t)Ee * 16);
    u32*     pkeys  = (u32*)alloc((size_t)Bb * 64 * 4);

    hipMemsetAsync(deg, 0, (size_t)Nn * 4, stream);
    hipMemsetAsync(cursor, 0, (size_t)Nn * 4, stream);
    hipMemsetAsync(pkeys, 0, (size_t)Bb * 64 * 4, stream);

    k_input_proj<<<12500, 256, 0, stream>>>(x, Win, bin, X);
    k_hist<<<(Ee + 255) / 256, 256, 0, stream>>>(ei, deg);
    k_part<<<SCB, 256, 0, stream>>>(deg, psum);
    k_scanp<<<1, 256, 0, stream>>>(psum, poff);
    k_apply<<<SCB, 256, 0, stream>>>(deg, poff, rowptr);
    k_scatter<<<(Ee + 255) / 256, 256, 0, stream>>>(ei, edge_attr, rowptr, cursor, colsrc, ea4);

    const int GB = 512;
    for (int l = 0; l < 3; ++l) {
        k_proj_kv<<<GB, 256, 0, stream>>>(X, KV, Wk + l * 4096, Wv + l * 4096,
            bk + l * 64, bv + l * 64, ln1g + l * 64, ln1b + l * 64);
        k_proj_qs<<<GB, 256, 0, stream>>>(X, QX, Wq + l * 4096, Wsk + l * 4096,
            bq + l * 64, bsk + l * 64, ln1g + l * 64, ln1b + l * 64);
        k_edge<<<Nn / 4, 256, 0, stream>>>(QX, KV, X, rowptr, colsrc, ea4,
            We + l * 256, Wbe + l * 192);
        k_ffn1_m<<<GB, 256, 0, stream>>>(X, G16, W1 + l * 8192, b1 + l * 128,
            ln2g + l * 64, ln2b + l * 64);
        k_ffn2_m<<<GB, 256, 0, stream>>>(G16, X, W2 + l * 8192, b2 + l * 64,
            batch, pkeys, (l == 2) ? 1 : 0);
    }
    k_head<<<Bb, 128, 0, stream>>>(pkeys, Wo1, bo1, Wo2, bo2, (float*)d_out);
}